// Round 17
// baseline (664.337 us; speedup 1.0000x reference)
//
#include <hip/hip_runtime.h>
#include <math.h>

#define NN 2048
#define NE 49152
#define WNUM 3328

typedef __attribute__((ext_vector_type(8))) _Float16 half8;
typedef __attribute__((ext_vector_type(4))) float f32x4;

__device__ __forceinline__ float silu_f(float x){ return x / (1.0f + expf(-x)); }
__device__ __forceinline__ float sigm_f(float x){ return 1.0f / (1.0f + expf(-x)); }

// ---------------- edge geometry: y1(3), Ay(9), rbf(8) -> egeo stride 20; + dst histogram ----
__global__ void geom_kernel(const float* __restrict__ pos, const int* __restrict__ ei,
                            float* __restrict__ egeo, int* __restrict__ cnt) {
  int e = blockIdx.x * 256 + threadIdx.x;
  if (e >= NE) return;
  int s = ei[e], d = ei[NE + e];
  atomicAdd(&cnt[d], 1);
  float rx = pos[d*3+0] - pos[s*3+0];
  float ry = pos[d*3+1] - pos[s*3+1];
  float rz = pos[d*3+2] - pos[s*3+2];
  float r = sqrtf(rx*rx + ry*ry + rz*rz);
  r = fmaxf(r, 1e-6f);
  float x = rx / r, y = ry / r, z = rz / r;
  const float s3 = 1.7320508075688772f;
  const float c15 = 3.872983346207417f;
  float y2_0 = c15 * x * y;
  float y2_1 = c15 * y * z;
  float y2_2 = 1.118033988749895f * (3.0f*z*z - 1.0f);
  float y2_3 = c15 * x * z;
  float y2_4 = 1.9364916731037085f * (x*x - y*y);
  const float q2 = 0.7071067811865476f;
  const float q6 = 0.4082482904638631f;
  float* g = egeo + (size_t)e * 20;
  g[0] = s3 * x; g[1] = s3 * y; g[2] = s3 * z;
  g[3+0] = -q6*y2_2 + q2*y2_4;
  g[3+1] =  q2*y2_0;
  g[3+2] =  q2*y2_3;
  g[3+3] =  q2*y2_0;
  g[3+4] = -q6*y2_2 - q2*y2_4;
  g[3+5] =  q2*y2_1;
  g[3+6] =  q2*y2_3;
  g[3+7] =  q2*y2_1;
  g[3+8] =  2.0f*q6*y2_2;
  float u = r / 6.0f;
  float fc = 0.0f;
  if (u < 1.0f) {
    float u2=u*u, u3=u2*u, u6=u3*u3, u7=u6*u, u8=u7*u;
    fc = 1.0f - 28.0f*u6 + 48.0f*u7 - 21.0f*u8;
  }
  const float pref = 0.5773502691896258f;
  const float pi6 = 0.5235987755982988f;
  #pragma unroll
  for (int n = 1; n <= 8; n++) {
    g[12 + n - 1] = pref * sinf((float)n * pi6 * r) / r * fc;
  }
}

// ---------------- CSR scan ----------------
__global__ void scan_kernel(const int* __restrict__ cnt, int* __restrict__ offs,
                            int* __restrict__ cursor) {
  __shared__ int part[256];
  int t = threadIdx.x;
  int local[8];
  int s = 0;
  #pragma unroll
  for (int j = 0; j < 8; j++) { local[j] = s; s += cnt[t*8 + j]; }
  part[t] = s;
  __syncthreads();
  for (int off = 1; off < 256; off <<= 1) {
    int v = part[t];
    int add = (t >= off) ? part[t - off] : 0;
    __syncthreads();
    part[t] = v + add;
    __syncthreads();
  }
  int excl = (t == 0) ? 0 : part[t-1];
  #pragma unroll
  for (int j = 0; j < 8; j++) {
    int o = excl + local[j];
    offs[t*8 + j] = o;
    cursor[t*8 + j] = o;
  }
  if (t == 255) offs[2048] = part[255];
}

// scatter: record each edge's CSR slot (epos) so edge_msg can write msg in CSR order
__global__ void scatter_kernel(const int* __restrict__ ei, int* __restrict__ cursor,
                               int* __restrict__ epos) {
  int e = blockIdx.x * 256 + threadIdx.x;
  if (e >= NE) return;
  int d = ei[NE + e];
  int p = atomicAdd(&cursor[d], 1);
  epos[e] = p;
}

// ---------------- W3 -> f16, MFMA-B-fragment-ordered ----------------
__global__ void conv_w3_kernel(const float* __restrict__ w3g, _Float16* __restrict__ w3h) {
  int tid = blockIdx.x * 256 + threadIdx.x;
  if (tid >= 16 * WNUM) return;
  int n = tid % WNUM;
  int lq = tid / WNUM;           // l*4 + quad
  int quad = lq & 3, l = lq >> 2;
  const float* src = w3g + (size_t)l * 64 * WNUM + n;
  int idx = n >> 4, L = n & 15;
  _Float16* dst = w3h + ((size_t)(l * 208 + idx) * 2) * 512 + (quad*16 + L) * 8;
  half8 h0, h1;
  #pragma unroll
  for (int j = 0; j < 8; j++) {
    h0[j] = (_Float16)src[(size_t)(quad*8 + j) * WNUM];
    h1[j] = (_Float16)src[(size_t)(32 + quad*8 + j) * WNUM];
  }
  *(half8*)(dst)       = h0;
  *(half8*)(dst + 512) = h1;
}

// ---------------- radial MLP for ALL layers -> f16 (one launch) ----------------
#define NBR1 (NE/16)
__global__ void radial_all_kernel(const float* __restrict__ egeo,
                                  const float* __restrict__ w1, const float* __restrict__ b1,
                                  const float* __restrict__ w2, const float* __restrict__ b2,
                                  _Float16* __restrict__ f_h) {
  __shared__ float h1s[16][64];
  int l = blockIdx.x / NBR1;
  int bb = blockIdx.x % NBR1;
  int ty = threadIdx.x >> 6, dk = threadIdx.x & 63;
  int e0b = bb * 16 + ty * 4;
  const float* w1l = w1 + (size_t)l * 8 * 64;
  const float* w2l = w2 + (size_t)l * 64 * 64;
  _Float16* fl = f_h + (size_t)l * NE * 64;
  float b1v = b1[l*64 + dk];
  #pragma unroll
  for (int k = 0; k < 4; ++k) {
    const float* rb = egeo + (size_t)(e0b + k) * 20 + 12;
    float acc = b1v;
    #pragma unroll
    for (int j = 0; j < 8; j++) acc += rb[j] * w1l[j*64 + dk];
    h1s[ty*4 + k][dk] = silu_f(acc);
  }
  __syncthreads();
  float b2v = b2[l*64 + dk];
  float o0 = b2v, o1 = b2v, o2 = b2v, o3 = b2v;
  #pragma unroll 8
  for (int j = 0; j < 64; ++j) {
    float w = w2l[j*64 + dk];
    o0 += h1s[ty*4+0][j] * w;
    o1 += h1s[ty*4+1][j] * w;
    o2 += h1s[ty*4+2][j] * w;
    o3 += h1s[ty*4+3][j] * w;
  }
  fl[(size_t)(e0b+0)*64 + dk] = (_Float16)silu_f(o0);
  fl[(size_t)(e0b+1)*64 + dk] = (_Float16)silu_f(o1);
  fl[(size_t)(e0b+2)*64 + dk] = (_Float16)silu_f(o2);
  fl[(size_t)(e0b+3)*64 + dk] = (_Float16)silu_f(o3);
}

// ---------------- embed + layer-0 node linears (h v-part = 0 => hx/xself v-part = 0) ---
__global__ void embed_prep_kernel(const float* __restrict__ x, const float* __restrict__ ew,
                                  const float* __restrict__ lws0, const float* __restrict__ sws0,
                                  float* __restrict__ h, float* __restrict__ hx,
                                  float* __restrict__ xself) {
  __shared__ float hs[8][32];
  int t = threadIdx.x;
  int nl = t >> 5, c = t & 31;
  int n = blockIdx.x * 8 + nl;
  float v = 0.0f;
  #pragma unroll
  for (int j = 0; j < 16; j++) v += x[n*16 + j] * ew[j*32 + c];
  v *= 0.25f;
  hs[nl][c] = v;
  h[(size_t)n*80 + c] = v;
  for (int idx = t; idx < 8*48; idx += 256) {
    int nn = blockIdx.x * 8 + idx / 48;
    h[(size_t)nn*80 + 32 + idx % 48] = 0.0f;
  }
  __syncthreads();
  for (int idx = t; idx < 2*8*80; idx += 256) {
    int which = idx / 640, r = idx % 640;
    int nl2 = r / 80, cc = r % 80;
    int n2 = blockIdx.x * 8 + nl2;
    float o = 0.0f;
    if (cc < 32) {
      const float* W = which ? sws0 : lws0;
      #pragma unroll 8
      for (int u = 0; u < 32; u++) o += hs[nl2][u] * W[u*32 + cc];
      o *= 0.17677669529663687f;
    }
    (which ? xself : hx)[(size_t)n2*80 + cc] = o;
  }
}

// ---------------- fused MFMA weight-GEMM (f16) + tensor product -> msg (CSR order) ----
// R16 + ONE change: wave load balance. Type4 (16 idx) split at u=8: wave2 takes
// u0-7, wave3 takes u8-15. Critical path 64 -> 56 idx per wave (waves 0/1 stay 48).
// Pool/barrier structure unchanged: w3's t4b loop reads vT BEFORE the barrier after
// which w2 overwrites that region as poolC. Register liveness pattern per wave is
// unchanged (~116 VGPR) — do NOT extend accumulator liveness (R15: spill at 128).
__launch_bounds__(256, 2)
__global__ void edge_msg_kernel(const int* __restrict__ ei, const float* __restrict__ egeo,
                                const _Float16* __restrict__ f_h,
                                const float* __restrict__ hx,
                                const _Float16* __restrict__ w3h,
                                const float* __restrict__ b3g,
                                const int* __restrict__ epos,
                                float* __restrict__ msg, int l) {
  __shared__ float smem[15616];            // 62.5 KB
  __shared__ int eposS[64];
  float* sT    = smem;                     // [32][64]
  float* p2T   = smem + 2048;              // [16][64]
  float* q3T   = smem + 3072;              // [48][64]  s_u * y1_i
  float* vT    = smem + 6144;              // [48][64]
  float* q5T   = smem + 9216;              // [48][64]
  float* biasL = smem + 12288;             // [3328]
  float* poolA = smem;                     // post-loop overlay (sT+p2T dead)
  float* poolB = smem + 3072;              // overlay (q3T dead)
  float* poolC = smem + 6144;              // overlay (vT dead)

  const int t = threadIdx.x;
  const int e0 = blockIdx.x * 64;
  const float* b3l = b3g + (size_t)l * WNUM;

  // ---- prologue ----
  for (int i = t; i < WNUM; i += 256) biasL[i] = b3l[i];
  if (t < 64) eposS[t] = epos[e0 + t];
  for (int idx = t; idx < 64*80; idx += 256) {
    int e = idx / 80, c = idx % 80;
    int src = ei[e0 + e];
    float val = hx[(size_t)src*80 + c];
    if (c < 32) sT[c*64 + e] = val; else vT[(c-32)*64 + e] = val;
  }
  __syncthreads();
  for (int idx = t; idx < 64*16; idx += 256) {
    int u = idx >> 6, e = idx & 63;
    const float* g = &egeo[(size_t)(e0+e)*20];
    float a = vT[(u*3)*64+e]*g[0] + vT[(u*3+1)*64+e]*g[1] + vT[(u*3+2)*64+e]*g[2];
    p2T[u*64 + e] = a * 0.5773502691896258f;
  }
  for (int idx = t; idx < 64*48; idx += 256) {
    int o = idx >> 6, e = idx & 63;
    int u = o / 3, jj = o % 3;
    const float* g = &egeo[(size_t)(e0+e)*20];
    q3T[o*64 + e] = sT[u*64 + e] * g[jj];
    float a = vT[(u*3)*64+e]*g[3+jj] + vT[(u*3+1)*64+e]*g[6+jj] + vT[(u*3+2)*64+e]*g[9+jj];
    q5T[o*64 + e] = a * 0.7745966692414834f;
  }

  const int wv = t >> 6, lane = t & 63, L = lane & 15, quad = lane >> 4;
  const int qb = quad * 4;

  // A fragments for all 4 edge-groups (32 VGPR)
  half8 Ah[4][2];
  #pragma unroll
  for (int g = 0; g < 4; ++g) {
    const half8* fA = (const half8*)(f_h + (size_t)(e0 + g*16 + L)*64);
    Ah[g][0] = fA[quad];
    Ah[g][1] = fA[4 + quad];
  }
  __syncthreads();   // LDS (factors + bias + epos) ready

  const _Float16* wb = w3h + (size_t)l * 208 * 1024 + lane * 8;
  half8 pb0[4], pb1[4];
  float bs[4];

#define PRIME(START)                                                          \
  { _Pragma("unroll")                                                         \
    for (int _s = 0; _s < 4; ++_s) {                                          \
      const _Float16* _wn = wb + (size_t)((START) + _s) * 1024;               \
      pb0[_s] = *(const half8*)_wn;                                           \
      pb1[_s] = *(const half8*)(_wn + 512);                                   \
      bs[_s] = biasL[((START) + _s)*16 + L];                                  \
    } }

  // declares a0..a3 (one per edge-group); CO compile-time
#define GCORE(IDX, CO, OKCOND)                                                \
  f32x4 a0, a1, a2, a3;                                                       \
  { half8 _B0 = pb0[(CO)&3], _B1 = pb1[(CO)&3];                               \
    float _bb = bs[(CO)&3];                                                   \
    if (OKCOND) {                                                             \
      const _Float16* _wn = wb + (size_t)((IDX) + 4) * 1024;                  \
      pb0[(CO)&3] = *(const half8*)_wn;                                       \
      pb1[(CO)&3] = *(const half8*)(_wn + 512);                               \
      bs[(CO)&3] = biasL[((IDX) + 4)*16 + L];                                 \
    }                                                                         \
    a0 = (f32x4){_bb,_bb,_bb,_bb}; a1 = a0; a2 = a0; a3 = a0;                 \
    a0 = __builtin_amdgcn_mfma_f32_16x16x32_f16(Ah[0][0], _B0, a0, 0,0,0);    \
    a0 = __builtin_amdgcn_mfma_f32_16x16x32_f16(Ah[0][1], _B1, a0, 0,0,0);    \
    a1 = __builtin_amdgcn_mfma_f32_16x16x32_f16(Ah[1][0], _B0, a1, 0,0,0);    \
    a1 = __builtin_amdgcn_mfma_f32_16x16x32_f16(Ah[1][1], _B1, a1, 0,0,0);    \
    a2 = __builtin_amdgcn_mfma_f32_16x16x32_f16(Ah[2][0], _B0, a2, 0,0,0);    \
    a2 = __builtin_amdgcn_mfma_f32_16x16x32_f16(Ah[2][1], _B1, a2, 0,0,0);    \
    a3 = __builtin_amdgcn_mfma_f32_16x16x32_f16(Ah[3][0], _B0, a3, 0,0,0);    \
    a3 = __builtin_amdgcn_mfma_f32_16x16x32_f16(Ah[3][1], _B1, a3, 0,0,0);    \
  }

  const float S48 = 0.14433756729740645f;  // 1/sqrt(48)
  const float S64 = 0.125f;                // 1/sqrt(64)

  if (wv <= 1) {
    f32x4 ms[4][3];
    #pragma unroll
    for (int g = 0; g < 4; ++g)
      #pragma unroll
      for (int j = 0; j < 3; ++j) ms[g][j] = (f32x4){0,0,0,0};
    const int ustart = wv * 16, istart = wv * 48, iend = istart + 48;
    PRIME(istart);
    for (int u4 = 0; u4 < 16; u4 += 4) {
      #pragma unroll
      for (int uu = 0; uu < 4; ++uu) {
        const int u = u4 + uu;
        f32x4 f0 = *(const f32x4*)&sT[(ustart+u)*64 + qb];
        f32x4 f1 = *(const f32x4*)&sT[(ustart+u)*64 + 16 + qb];
        f32x4 f2 = *(const f32x4*)&sT[(ustart+u)*64 + 32 + qb];
        f32x4 f3 = *(const f32x4*)&sT[(ustart+u)*64 + 48 + qb];
        #pragma unroll
        for (int j = 0; j < 3; ++j) {
          const int CO = uu*3 + j;
          const int idx = istart + u4*3 + CO;
          GCORE(idx, CO, idx + 4 < iend);
          ms[0][j] += f0*a0; ms[1][j] += f1*a1; ms[2][j] += f2*a2; ms[3][j] += f3*a3;
        }
      }
    }
    float* pool = (wv == 0) ? poolA : poolB;
    __syncthreads();
    #pragma unroll
    for (int g = 0; g < 4; ++g)
      #pragma unroll
      for (int j = 0; j < 3; ++j)
        #pragma unroll
        for (int r = 0; r < 4; ++r)
          pool[(g*16 + qb + r)*48 + j*16 + L] = ms[g][j][r];
    __syncthreads();
  } else if (wv == 2) {
    f32x4 ms[4][3], mv[4][3];
    #pragma unroll
    for (int g = 0; g < 4; ++g)
      #pragma unroll
      for (int j = 0; j < 3; ++j) { ms[g][j] = (f32x4){0,0,0,0}; mv[g][j] = (f32x4){0,0,0,0}; }
    PRIME(96);
    for (int u4 = 0; u4 < 16; u4 += 4) {
      #pragma unroll
      for (int uu = 0; uu < 4; ++uu) {
        const int u = u4 + uu;
        f32x4 f0 = *(const f32x4*)&p2T[u*64 + qb];
        f32x4 f1 = *(const f32x4*)&p2T[u*64 + 16 + qb];
        f32x4 f2 = *(const f32x4*)&p2T[u*64 + 32 + qb];
        f32x4 f3 = *(const f32x4*)&p2T[u*64 + 48 + qb];
        #pragma unroll
        for (int j = 0; j < 3; ++j) {
          const int CO = uu*3 + j;
          const int idx = 96 + u4*3 + CO;
          GCORE(idx, CO, idx + 4 < 144);
          ms[0][j] += f0*a0; ms[1][j] += f1*a1; ms[2][j] += f2*a2; ms[3][j] += f3*a3;
        }
      }
    }
    // type4 first half: u 0..7 (idx 176..183)
    PRIME(176);
    for (int u4 = 0; u4 < 8; u4 += 4) {
      #pragma unroll
      for (int uu = 0; uu < 4; ++uu) {
        const int u = u4 + uu;
        const int idx = 176 + u;
        GCORE(idx, uu, idx + 4 < 184);
        #pragma unroll
        for (int i = 0; i < 3; ++i) {
          mv[0][i] += *(const f32x4*)&vT[(u*3+i)*64 + qb]      * a0;
          mv[1][i] += *(const f32x4*)&vT[(u*3+i)*64 + 16 + qb] * a1;
          mv[2][i] += *(const f32x4*)&vT[(u*3+i)*64 + 32 + qb] * a2;
          mv[3][i] += *(const f32x4*)&vT[(u*3+i)*64 + 48 + qb] * a3;
        }
      }
    }
    __syncthreads();
    #pragma unroll
    for (int g = 0; g < 4; ++g)
      #pragma unroll
      for (int i = 0; i < 3; ++i)
        #pragma unroll
        for (int r = 0; r < 4; ++r)
          poolC[(g*16 + qb + r)*48 + i*16 + L] = mv[g][i][r];
    __syncthreads();
    #pragma unroll
    for (int g = 0; g < 4; ++g) {
      #pragma unroll
      for (int r = 0; r < 4; ++r) {
        const int eb = g*16 + qb + r;
        float* mp = msg + (size_t)eposS[eb]*96;
        #pragma unroll
        for (int j = 0; j < 3; ++j)
          mp[j*16 + L] = (ms[g][j][r] + poolA[eb*48 + j*16 + L] + poolB[eb*48 + j*16 + L]) * S48;
      }
    }
  } else {
    f32x4 mv[4][3];
    #pragma unroll
    for (int g = 0; g < 4; ++g)
      #pragma unroll
      for (int i = 0; i < 3; ++i) mv[g][i] = (f32x4){0,0,0,0};
    PRIME(144);
    for (int u4 = 0; u4 < 32; u4 += 4) {
      #pragma unroll
      for (int uu = 0; uu < 4; ++uu) {
        const int u = u4 + uu;
        const int idx = 144 + u;
        GCORE(idx, uu, idx + 4 < 176);
        #pragma unroll
        for (int i = 0; i < 3; ++i) {
          mv[0][i] += *(const f32x4*)&q3T[(u*3+i)*64 + qb]      * a0;
          mv[1][i] += *(const f32x4*)&q3T[(u*3+i)*64 + 16 + qb] * a1;
          mv[2][i] += *(const f32x4*)&q3T[(u*3+i)*64 + 32 + qb] * a2;
          mv[3][i] += *(const f32x4*)&q3T[(u*3+i)*64 + 48 + qb] * a3;
        }
      }
    }
    // type4 second half: u 8..15 (idx 184..191) — vT still live (poolC overlay
    // happens only after the barrier below)
    PRIME(184);
    for (int u4 = 8; u4 < 16; u4 += 4) {
      #pragma unroll
      for (int uu = 0; uu < 4; ++uu) {
        const int u = u4 + uu;
        const int idx = 176 + u;
        GCORE(idx, uu, idx + 4 < 192);
        #pragma unroll
        for (int i = 0; i < 3; ++i) {
          mv[0][i] += *(const f32x4*)&vT[(u*3+i)*64 + qb]      * a0;
          mv[1][i] += *(const f32x4*)&vT[(u*3+i)*64 + 16 + qb] * a1;
          mv[2][i] += *(const f32x4*)&vT[(u*3+i)*64 + 32 + qb] * a2;
          mv[3][i] += *(const f32x4*)&vT[(u*3+i)*64 + 48 + qb] * a3;
        }
      }
    }
    PRIME(192);
    for (int u4 = 0; u4 < 16; u4 += 4) {
      #pragma unroll
      for (int uu = 0; uu < 4; ++uu) {
        const int u = u4 + uu;
        const int idx = 192 + u;
        GCORE(idx, uu, idx + 4 < 208);
        #pragma unroll
        for (int i = 0; i < 3; ++i) {
          mv[0][i] += *(const f32x4*)&q5T[(u*3+i)*64 + qb]      * a0;
          mv[1][i] += *(const f32x4*)&q5T[(u*3+i)*64 + 16 + qb] * a1;
          mv[2][i] += *(const f32x4*)&q5T[(u*3+i)*64 + 32 + qb] * a2;
          mv[3][i] += *(const f32x4*)&q5T[(u*3+i)*64 + 48 + qb] * a3;
        }
      }
    }
    __syncthreads();
    __syncthreads();
    #pragma unroll
    for (int g = 0; g < 4; ++g) {
      #pragma unroll
      for (int r = 0; r < 4; ++r) {
        const int eb = g*16 + qb + r;
        float* mp = msg + (size_t)eposS[eb]*96;
        #pragma unroll
        for (int i = 0; i < 3; ++i)
          mp[48 + 3*L + i] = (mv[g][i][r] + poolC[eb*48 + i*16 + L]) * S64;
      }
    }
  }
#undef GCORE
#undef PRIME
}

// ---------------- fused: CSR-streaming gather + node update + next node linears / proj --
__global__ void agg_fused_kernel(const float* __restrict__ msg, const int* __restrict__ offs,
                                 const float* __restrict__ xself_in, float* __restrict__ h,
                                 const float* __restrict__ lwsN, const float* __restrict__ lwvN,
                                 const float* __restrict__ swsN, const float* __restrict__ swvN,
                                 float* __restrict__ hx_out, float* __restrict__ xself_out,
                                 const float* __restrict__ pw, float* __restrict__ out,
                                 int last) {
  __shared__ float sagg[4][96];
  __shared__ float hnew[4][80];
  int t = threadIdx.x;
  int nb = blockIdx.x * 4;
  for (int idx = t; idx < 4*96; idx += 256) {
    int nl = idx / 96, c = idx % 96;
    int n = nb + nl;
    int b = offs[n], e = offs[n+1];
    float acc = 0.0f, acc2 = 0.0f;
    int j = b;
    for (; j + 1 < e; j += 2) {
      acc  += msg[(size_t)j*96 + c];
      acc2 += msg[(size_t)(j+1)*96 + c];
    }
    if (j < e) acc += msg[(size_t)j*96 + c];
    sagg[nl][c] = (acc + acc2) * 0.20412414523193154f;   // 1/sqrt(24)
  }
  __syncthreads();
  for (int idx = t; idx < 4*80; idx += 256) {
    int nl = idx / 80, c = idx % 80;
    int n = nb + nl;
    float a;
    if (c < 32) {
      a = silu_f(sagg[nl][c]);
    } else {
      int oc = c - 32, wch = oc / 3;
      a = sagg[nl][48 + oc] * sigm_f(sagg[nl][32 + wch]);
    }
    float hn = h[(size_t)n*80 + c] + xself_in[(size_t)n*80 + c] + a;
    hnew[nl][c] = hn;
    h[(size_t)n*80 + c] = hn;
  }
  __syncthreads();
  if (!last) {
    for (int idx = t; idx < 2*4*80; idx += 256) {
      int which = idx / 320, r = idx % 320;
      int nl = r / 80, c = r % 80;
      int n = nb + nl;
      const float* Ws = which ? swsN : lwsN;
      const float* Wv = which ? swvN : lwvN;
      float v = 0.0f;
      if (c < 32) {
        #pragma unroll 8
        for (int u = 0; u < 32; u++) v += hnew[nl][u] * Ws[u*32 + c];
        v *= 0.17677669529663687f;
      } else {
        int oc = c - 32, wch = oc / 3, i = oc % 3;
        #pragma unroll
        for (int u = 0; u < 16; u++) v += hnew[nl][32 + u*3 + i] * Wv[u*16 + wch];
        v *= 0.25f;
      }
      (which ? xself_out : hx_out)[(size_t)n*80 + c] = v;
    }
  } else {
    for (int idx = t; idx < 4*32; idx += 256) {
      int nl = idx / 32, c = idx % 32;
      int n = nb + nl;
      float acc = 0.0f;
      #pragma unroll 8
      for (int u = 0; u < 32; u++) acc += hnew[nl][u] * pw[u*32 + c];
      out[(size_t)n*32 + c] = acc * 0.17677669529663687f;
    }
  }
}

extern "C" void kernel_launch(void* const* d_in, const int* in_sizes, int n_in,
                              void* d_out, int out_size, void* d_ws, size_t ws_size,
                              hipStream_t stream) {
  const float* x       = (const float*)d_in[0];
  const float* pos     = (const float*)d_in[1];
  const int*   ei      = (const int*)  d_in[2];
  const float* embed_w = (const float*)d_in[3];
  const float* proj_w  = (const float*)d_in[4];
  const float* lin_ws  = (const float*)d_in[5];
  const float* lin_wv  = (const float*)d_in[6];
  const float* sc_ws   = (const float*)d_in[7];
  const float* sc_wv   = (const float*)d_in[8];
  const float* mlp_w1  = (const float*)d_in[9];
  const float* mlp_b1  = (const float*)d_in[10];
  const float* mlp_w2  = (const float*)d_in[11];
  const float* mlp_b2  = (const float*)d_in[12];
  const float* mlp_w3  = (const float*)d_in[13];
  const float* mlp_b3  = (const float*)d_in[14];
  float* out = (float*)d_out;

  float* ws    = (float*)d_ws;
  float* egeo  = ws;                          // NE*20
  float* h     = egeo  + (size_t)NE*20;       // NN*80
  float* hx    = h     + (size_t)NN*80;       // NN*80
  float* xself = hx    + (size_t)NN*80;       // NN*80
  float* msg   = xself + (size_t)NN*80;       // NE*96 (CSR-ordered rows)
  _Float16* f_h = (_Float16*)(msg + (size_t)NE*96);   // 4*NE*64 f16 (all layers)
  _Float16* w3h = f_h + (size_t)4*NE*64;              // 4*208*1024 f16
  int* cnt    = (int*)(w3h + (size_t)4*208*1024);     // NN
  int* offs   = cnt + NN;                     // NN+1
  int* cursor = offs + NN + 1;                // NN
  int* epos   = cursor + NN;                  // NE

  hipMemsetAsync(cnt, 0, NN*sizeof(int), stream);
  geom_kernel<<<(NE + 255)/256, 256, 0, stream>>>(pos, ei, egeo, cnt);
  scan_kernel<<<1, 256, 0, stream>>>(cnt, offs, cursor);
  scatter_kernel<<<NE/256, 256, 0, stream>>>(ei, cursor, epos);
  conv_w3_kernel<<<(16*WNUM + 255)/256, 256, 0, stream>>>(mlp_w3, w3h);
  radial_all_kernel<<<NBR1*4, 256, 0, stream>>>(egeo, mlp_w1, mlp_b1, mlp_w2, mlp_b2, f_h);
  embed_prep_kernel<<<NN/8, 256, 0, stream>>>(x, embed_w, lin_ws, sc_ws, h, hx, xself);

  for (int l = 0; l < 4; l++) {
    edge_msg_kernel<<<NE/64, 256, 0, stream>>>(ei, egeo, f_h + (size_t)l*NE*64, hx,
                                               w3h, mlp_b3, epos, msg, l);
    int last = (l == 3);
    agg_fused_kernel<<<NN/4, 256, 0, stream>>>(
        msg, offs, xself, h,
        lin_ws + (size_t)(l+1 < 4 ? l+1 : 0) * 1024,
        lin_wv + (size_t)(l+1 < 4 ? l+1 : 0) * 256,
        sc_ws  + (size_t)(l+1 < 4 ? l+1 : 0) * 1024,
        sc_wv  + (size_t)(l+1 < 4 ? l+1 : 0) * 256,
        hx, xself, proj_w, out, last);
  }
}

// Round 18
// 463.846 us; speedup vs baseline: 1.4322x; 1.4322x over previous
//
#include <hip/hip_runtime.h>
#include <math.h>

#define NN 2048
#define NE 49152
#define WNUM 3328

typedef __attribute__((ext_vector_type(8))) _Float16 half8;
typedef __attribute__((ext_vector_type(4))) float f32x4;

__device__ __forceinline__ float silu_f(float x){ return x / (1.0f + expf(-x)); }
__device__ __forceinline__ float sigm_f(float x){ return 1.0f / (1.0f + expf(-x)); }

// ---------------- edge geometry: y1(3), Ay(9), rbf(8) -> egeo stride 20; + dst histogram ----
__global__ void geom_kernel(const float* __restrict__ pos, const int* __restrict__ ei,
                            float* __restrict__ egeo, int* __restrict__ cnt) {
  int e = blockIdx.x * 256 + threadIdx.x;
  if (e >= NE) return;
  int s = ei[e], d = ei[NE + e];
  atomicAdd(&cnt[d], 1);
  float rx = pos[d*3+0] - pos[s*3+0];
  float ry = pos[d*3+1] - pos[s*3+1];
  float rz = pos[d*3+2] - pos[s*3+2];
  float r = sqrtf(rx*rx + ry*ry + rz*rz);
  r = fmaxf(r, 1e-6f);
  float x = rx / r, y = ry / r, z = rz / r;
  const float s3 = 1.7320508075688772f;
  const float c15 = 3.872983346207417f;
  float y2_0 = c15 * x * y;
  float y2_1 = c15 * y * z;
  float y2_2 = 1.118033988749895f * (3.0f*z*z - 1.0f);
  float y2_3 = c15 * x * z;
  float y2_4 = 1.9364916731037085f * (x*x - y*y);
  const float q2 = 0.7071067811865476f;
  const float q6 = 0.4082482904638631f;
  float* g = egeo + (size_t)e * 20;
  g[0] = s3 * x; g[1] = s3 * y; g[2] = s3 * z;
  g[3+0] = -q6*y2_2 + q2*y2_4;
  g[3+1] =  q2*y2_0;
  g[3+2] =  q2*y2_3;
  g[3+3] =  q2*y2_0;
  g[3+4] = -q6*y2_2 - q2*y2_4;
  g[3+5] =  q2*y2_1;
  g[3+6] =  q2*y2_3;
  g[3+7] =  q2*y2_1;
  g[3+8] =  2.0f*q6*y2_2;
  float u = r / 6.0f;
  float fc = 0.0f;
  if (u < 1.0f) {
    float u2=u*u, u3=u2*u, u6=u3*u3, u7=u6*u, u8=u7*u;
    fc = 1.0f - 28.0f*u6 + 48.0f*u7 - 21.0f*u8;
  }
  const float pref = 0.5773502691896258f;
  const float pi6 = 0.5235987755982988f;
  #pragma unroll
  for (int n = 1; n <= 8; n++) {
    g[12 + n - 1] = pref * sinf((float)n * pi6 * r) / r * fc;
  }
}

// ---------------- CSR scan ----------------
__global__ void scan_kernel(const int* __restrict__ cnt, int* __restrict__ offs,
                            int* __restrict__ cursor) {
  __shared__ int part[256];
  int t = threadIdx.x;
  int local[8];
  int s = 0;
  #pragma unroll
  for (int j = 0; j < 8; j++) { local[j] = s; s += cnt[t*8 + j]; }
  part[t] = s;
  __syncthreads();
  for (int off = 1; off < 256; off <<= 1) {
    int v = part[t];
    int add = (t >= off) ? part[t - off] : 0;
    __syncthreads();
    part[t] = v + add;
    __syncthreads();
  }
  int excl = (t == 0) ? 0 : part[t-1];
  #pragma unroll
  for (int j = 0; j < 8; j++) {
    int o = excl + local[j];
    offs[t*8 + j] = o;
    cursor[t*8 + j] = o;
  }
  if (t == 255) offs[2048] = part[255];
}

// scatter: record each edge's CSR slot (epos) so edge_msg can write msg in CSR order
__global__ void scatter_kernel(const int* __restrict__ ei, int* __restrict__ cursor,
                               int* __restrict__ epos) {
  int e = blockIdx.x * 256 + threadIdx.x;
  if (e >= NE) return;
  int d = ei[NE + e];
  int p = atomicAdd(&cursor[d], 1);
  epos[e] = p;
}

// ---------------- W3 -> f16, MFMA-B-fragment-ordered ----------------
__global__ void conv_w3_kernel(const float* __restrict__ w3g, _Float16* __restrict__ w3h) {
  int tid = blockIdx.x * 256 + threadIdx.x;
  if (tid >= 16 * WNUM) return;
  int n = tid % WNUM;
  int lq = tid / WNUM;           // l*4 + quad
  int quad = lq & 3, l = lq >> 2;
  const float* src = w3g + (size_t)l * 64 * WNUM + n;
  int idx = n >> 4, L = n & 15;
  _Float16* dst = w3h + ((size_t)(l * 208 + idx) * 2) * 512 + (quad*16 + L) * 8;
  half8 h0, h1;
  #pragma unroll
  for (int j = 0; j < 8; j++) {
    h0[j] = (_Float16)src[(size_t)(quad*8 + j) * WNUM];
    h1[j] = (_Float16)src[(size_t)(32 + quad*8 + j) * WNUM];
  }
  *(half8*)(dst)       = h0;
  *(half8*)(dst + 512) = h1;
}

// ---------------- radial MLP for ALL layers -> f16 (one launch) ----------------
#define NBR1 (NE/16)
__global__ void radial_all_kernel(const float* __restrict__ egeo,
                                  const float* __restrict__ w1, const float* __restrict__ b1,
                                  const float* __restrict__ w2, const float* __restrict__ b2,
                                  _Float16* __restrict__ f_h) {
  __shared__ float h1s[16][64];
  int l = blockIdx.x / NBR1;
  int bb = blockIdx.x % NBR1;
  int ty = threadIdx.x >> 6, dk = threadIdx.x & 63;
  int e0b = bb * 16 + ty * 4;
  const float* w1l = w1 + (size_t)l * 8 * 64;
  const float* w2l = w2 + (size_t)l * 64 * 64;
  _Float16* fl = f_h + (size_t)l * NE * 64;
  float b1v = b1[l*64 + dk];
  #pragma unroll
  for (int k = 0; k < 4; ++k) {
    const float* rb = egeo + (size_t)(e0b + k) * 20 + 12;
    float acc = b1v;
    #pragma unroll
    for (int j = 0; j < 8; j++) acc += rb[j] * w1l[j*64 + dk];
    h1s[ty*4 + k][dk] = silu_f(acc);
  }
  __syncthreads();
  float b2v = b2[l*64 + dk];
  float o0 = b2v, o1 = b2v, o2 = b2v, o3 = b2v;
  #pragma unroll 8
  for (int j = 0; j < 64; ++j) {
    float w = w2l[j*64 + dk];
    o0 += h1s[ty*4+0][j] * w;
    o1 += h1s[ty*4+1][j] * w;
    o2 += h1s[ty*4+2][j] * w;
    o3 += h1s[ty*4+3][j] * w;
  }
  fl[(size_t)(e0b+0)*64 + dk] = (_Float16)silu_f(o0);
  fl[(size_t)(e0b+1)*64 + dk] = (_Float16)silu_f(o1);
  fl[(size_t)(e0b+2)*64 + dk] = (_Float16)silu_f(o2);
  fl[(size_t)(e0b+3)*64 + dk] = (_Float16)silu_f(o3);
}

// ---------------- embed + layer-0 node linears (h v-part = 0 => hx/xself v-part = 0) ---
__global__ void embed_prep_kernel(const float* __restrict__ x, const float* __restrict__ ew,
                                  const float* __restrict__ lws0, const float* __restrict__ sws0,
                                  float* __restrict__ h, float* __restrict__ hx,
                                  float* __restrict__ xself) {
  __shared__ float hs[8][32];
  int t = threadIdx.x;
  int nl = t >> 5, c = t & 31;
  int n = blockIdx.x * 8 + nl;
  float v = 0.0f;
  #pragma unroll
  for (int j = 0; j < 16; j++) v += x[n*16 + j] * ew[j*32 + c];
  v *= 0.25f;
  hs[nl][c] = v;
  h[(size_t)n*80 + c] = v;
  for (int idx = t; idx < 8*48; idx += 256) {
    int nn = blockIdx.x * 8 + idx / 48;
    h[(size_t)nn*80 + 32 + idx % 48] = 0.0f;
  }
  __syncthreads();
  for (int idx = t; idx < 2*8*80; idx += 256) {
    int which = idx / 640, r = idx % 640;
    int nl2 = r / 80, cc = r % 80;
    int n2 = blockIdx.x * 8 + nl2;
    float o = 0.0f;
    if (cc < 32) {
      const float* W = which ? sws0 : lws0;
      #pragma unroll 8
      for (int u = 0; u < 32; u++) o += hs[nl2][u] * W[u*32 + cc];
      o *= 0.17677669529663687f;
    }
    (which ? xself : hx)[(size_t)n2*80 + cc] = o;
  }
}

// ---------------- fused MFMA weight-GEMM (f16) + tensor product -> msg (CSR order) ----
// R16-EXACT — FROZEN. 457 us total, edge_msg 65 us/layer, VGPR 116, no spill.
// Evidence (R15, R17): ANY restructuring of the K-loop branches tips the register
// allocator over the 128-VGPR cliff -> 3-6x scratch-spill regression. Do not touch.
__launch_bounds__(256, 2)
__global__ void edge_msg_kernel(const int* __restrict__ ei, const float* __restrict__ egeo,
                                const _Float16* __restrict__ f_h,
                                const float* __restrict__ hx,
                                const _Float16* __restrict__ w3h,
                                const float* __restrict__ b3g,
                                const int* __restrict__ epos,
                                float* __restrict__ msg, int l) {
  __shared__ float smem[15616];            // 62.5 KB
  __shared__ int eposS[64];
  float* sT    = smem;                     // [32][64]
  float* p2T   = smem + 2048;              // [16][64]
  float* q3T   = smem + 3072;              // [48][64]  s_u * y1_i
  float* vT    = smem + 6144;              // [48][64]
  float* q5T   = smem + 9216;              // [48][64]
  float* biasL = smem + 12288;             // [3328]
  float* poolA = smem;                     // post-loop overlay (sT+p2T dead)
  float* poolB = smem + 3072;              // overlay (q3T dead)
  float* poolC = smem + 6144;              // overlay (vT dead)

  const int t = threadIdx.x;
  const int e0 = blockIdx.x * 64;
  const float* b3l = b3g + (size_t)l * WNUM;

  // ---- prologue ----
  for (int i = t; i < WNUM; i += 256) biasL[i] = b3l[i];
  if (t < 64) eposS[t] = epos[e0 + t];
  for (int idx = t; idx < 64*80; idx += 256) {
    int e = idx / 80, c = idx % 80;
    int src = ei[e0 + e];
    float val = hx[(size_t)src*80 + c];
    if (c < 32) sT[c*64 + e] = val; else vT[(c-32)*64 + e] = val;
  }
  __syncthreads();
  for (int idx = t; idx < 64*16; idx += 256) {
    int u = idx >> 6, e = idx & 63;
    const float* g = &egeo[(size_t)(e0+e)*20];
    float a = vT[(u*3)*64+e]*g[0] + vT[(u*3+1)*64+e]*g[1] + vT[(u*3+2)*64+e]*g[2];
    p2T[u*64 + e] = a * 0.5773502691896258f;
  }
  for (int idx = t; idx < 64*48; idx += 256) {
    int o = idx >> 6, e = idx & 63;
    int u = o / 3, jj = o % 3;
    const float* g = &egeo[(size_t)(e0+e)*20];
    q3T[o*64 + e] = sT[u*64 + e] * g[jj];
    float a = vT[(u*3)*64+e]*g[3+jj] + vT[(u*3+1)*64+e]*g[6+jj] + vT[(u*3+2)*64+e]*g[9+jj];
    q5T[o*64 + e] = a * 0.7745966692414834f;
  }

  const int wv = t >> 6, lane = t & 63, L = lane & 15, quad = lane >> 4;
  const int qb = quad * 4;

  // A fragments for all 4 edge-groups (32 VGPR)
  half8 Ah[4][2];
  #pragma unroll
  for (int g = 0; g < 4; ++g) {
    const half8* fA = (const half8*)(f_h + (size_t)(e0 + g*16 + L)*64);
    Ah[g][0] = fA[quad];
    Ah[g][1] = fA[4 + quad];
  }
  __syncthreads();   // LDS (factors + bias + epos) ready

  const _Float16* wb = w3h + (size_t)l * 208 * 1024 + lane * 8;
  half8 pb0[4], pb1[4];
  float bs[4];

#define PRIME(START)                                                          \
  { _Pragma("unroll")                                                         \
    for (int _s = 0; _s < 4; ++_s) {                                          \
      const _Float16* _wn = wb + (size_t)((START) + _s) * 1024;               \
      pb0[_s] = *(const half8*)_wn;                                           \
      pb1[_s] = *(const half8*)(_wn + 512);                                   \
      bs[_s] = biasL[((START) + _s)*16 + L];                                  \
    } }

  // declares a0..a3 (one per edge-group); CO compile-time
#define GCORE(IDX, CO, OKCOND)                                                \
  f32x4 a0, a1, a2, a3;                                                       \
  { half8 _B0 = pb0[(CO)&3], _B1 = pb1[(CO)&3];                               \
    float _bb = bs[(CO)&3];                                                   \
    if (OKCOND) {                                                             \
      const _Float16* _wn = wb + (size_t)((IDX) + 4) * 1024;                  \
      pb0[(CO)&3] = *(const half8*)_wn;                                       \
      pb1[(CO)&3] = *(const half8*)(_wn + 512);                               \
      bs[(CO)&3] = biasL[((IDX) + 4)*16 + L];                                 \
    }                                                                         \
    a0 = (f32x4){_bb,_bb,_bb,_bb}; a1 = a0; a2 = a0; a3 = a0;                 \
    a0 = __builtin_amdgcn_mfma_f32_16x16x32_f16(Ah[0][0], _B0, a0, 0,0,0);    \
    a0 = __builtin_amdgcn_mfma_f32_16x16x32_f16(Ah[0][1], _B1, a0, 0,0,0);    \
    a1 = __builtin_amdgcn_mfma_f32_16x16x32_f16(Ah[1][0], _B0, a1, 0,0,0);    \
    a1 = __builtin_amdgcn_mfma_f32_16x16x32_f16(Ah[1][1], _B1, a1, 0,0,0);    \
    a2 = __builtin_amdgcn_mfma_f32_16x16x32_f16(Ah[2][0], _B0, a2, 0,0,0);    \
    a2 = __builtin_amdgcn_mfma_f32_16x16x32_f16(Ah[2][1], _B1, a2, 0,0,0);    \
    a3 = __builtin_amdgcn_mfma_f32_16x16x32_f16(Ah[3][0], _B0, a3, 0,0,0);    \
    a3 = __builtin_amdgcn_mfma_f32_16x16x32_f16(Ah[3][1], _B1, a3, 0,0,0);    \
  }

  const float S48 = 0.14433756729740645f;  // 1/sqrt(48)
  const float S64 = 0.125f;                // 1/sqrt(64)

  if (wv <= 1) {
    f32x4 ms[4][3];
    #pragma unroll
    for (int g = 0; g < 4; ++g)
      #pragma unroll
      for (int j = 0; j < 3; ++j) ms[g][j] = (f32x4){0,0,0,0};
    const int ustart = wv * 16, istart = wv * 48, iend = istart + 48;
    PRIME(istart);
    for (int u4 = 0; u4 < 16; u4 += 4) {
      #pragma unroll
      for (int uu = 0; uu < 4; ++uu) {
        const int u = u4 + uu;
        f32x4 f0 = *(const f32x4*)&sT[(ustart+u)*64 + qb];
        f32x4 f1 = *(const f32x4*)&sT[(ustart+u)*64 + 16 + qb];
        f32x4 f2 = *(const f32x4*)&sT[(ustart+u)*64 + 32 + qb];
        f32x4 f3 = *(const f32x4*)&sT[(ustart+u)*64 + 48 + qb];
        #pragma unroll
        for (int j = 0; j < 3; ++j) {
          const int CO = uu*3 + j;
          const int idx = istart + u4*3 + CO;
          GCORE(idx, CO, idx + 4 < iend);
          ms[0][j] += f0*a0; ms[1][j] += f1*a1; ms[2][j] += f2*a2; ms[3][j] += f3*a3;
        }
      }
    }
    float* pool = (wv == 0) ? poolA : poolB;
    __syncthreads();
    #pragma unroll
    for (int g = 0; g < 4; ++g)
      #pragma unroll
      for (int j = 0; j < 3; ++j)
        #pragma unroll
        for (int r = 0; r < 4; ++r)
          pool[(g*16 + qb + r)*48 + j*16 + L] = ms[g][j][r];
    __syncthreads();
  } else if (wv == 2) {
    f32x4 ms[4][3], mv[4][3];
    #pragma unroll
    for (int g = 0; g < 4; ++g)
      #pragma unroll
      for (int j = 0; j < 3; ++j) { ms[g][j] = (f32x4){0,0,0,0}; mv[g][j] = (f32x4){0,0,0,0}; }
    PRIME(96);
    for (int u4 = 0; u4 < 16; u4 += 4) {
      #pragma unroll
      for (int uu = 0; uu < 4; ++uu) {
        const int u = u4 + uu;
        f32x4 f0 = *(const f32x4*)&p2T[u*64 + qb];
        f32x4 f1 = *(const f32x4*)&p2T[u*64 + 16 + qb];
        f32x4 f2 = *(const f32x4*)&p2T[u*64 + 32 + qb];
        f32x4 f3 = *(const f32x4*)&p2T[u*64 + 48 + qb];
        #pragma unroll
        for (int j = 0; j < 3; ++j) {
          const int CO = uu*3 + j;
          const int idx = 96 + u4*3 + CO;
          GCORE(idx, CO, idx + 4 < 144);
          ms[0][j] += f0*a0; ms[1][j] += f1*a1; ms[2][j] += f2*a2; ms[3][j] += f3*a3;
        }
      }
    }
    PRIME(176);
    for (int u4 = 0; u4 < 16; u4 += 4) {
      #pragma unroll
      for (int uu = 0; uu < 4; ++uu) {
        const int u = u4 + uu;
        const int idx = 176 + u;
        GCORE(idx, uu, idx + 4 < 192);
        #pragma unroll
        for (int i = 0; i < 3; ++i) {
          mv[0][i] += *(const f32x4*)&vT[(u*3+i)*64 + qb]      * a0;
          mv[1][i] += *(const f32x4*)&vT[(u*3+i)*64 + 16 + qb] * a1;
          mv[2][i] += *(const f32x4*)&vT[(u*3+i)*64 + 32 + qb] * a2;
          mv[3][i] += *(const f32x4*)&vT[(u*3+i)*64 + 48 + qb] * a3;
        }
      }
    }
    __syncthreads();
    #pragma unroll
    for (int g = 0; g < 4; ++g)
      #pragma unroll
      for (int i = 0; i < 3; ++i)
        #pragma unroll
        for (int r = 0; r < 4; ++r)
          poolC[(g*16 + qb + r)*48 + i*16 + L] = mv[g][i][r];
    __syncthreads();
    #pragma unroll
    for (int g = 0; g < 4; ++g) {
      #pragma unroll
      for (int r = 0; r < 4; ++r) {
        const int eb = g*16 + qb + r;
        float* mp = msg + (size_t)eposS[eb]*96;
        #pragma unroll
        for (int j = 0; j < 3; ++j)
          mp[j*16 + L] = (ms[g][j][r] + poolA[eb*48 + j*16 + L] + poolB[eb*48 + j*16 + L]) * S48;
      }
    }
  } else {
    f32x4 mv[4][3];
    #pragma unroll
    for (int g = 0; g < 4; ++g)
      #pragma unroll
      for (int i = 0; i < 3; ++i) mv[g][i] = (f32x4){0,0,0,0};
    PRIME(144);
    for (int u4 = 0; u4 < 32; u4 += 4) {
      #pragma unroll
      for (int uu = 0; uu < 4; ++uu) {
        const int u = u4 + uu;
        const int idx = 144 + u;
        GCORE(idx, uu, idx + 4 < 176);
        #pragma unroll
        for (int i = 0; i < 3; ++i) {
          mv[0][i] += *(const f32x4*)&q3T[(u*3+i)*64 + qb]      * a0;
          mv[1][i] += *(const f32x4*)&q3T[(u*3+i)*64 + 16 + qb] * a1;
          mv[2][i] += *(const f32x4*)&q3T[(u*3+i)*64 + 32 + qb] * a2;
          mv[3][i] += *(const f32x4*)&q3T[(u*3+i)*64 + 48 + qb] * a3;
        }
      }
    }
    PRIME(192);
    for (int u4 = 0; u4 < 16; u4 += 4) {
      #pragma unroll
      for (int uu = 0; uu < 4; ++uu) {
        const int u = u4 + uu;
        const int idx = 192 + u;
        GCORE(idx, uu, idx + 4 < 208);
        #pragma unroll
        for (int i = 0; i < 3; ++i) {
          mv[0][i] += *(const f32x4*)&q5T[(u*3+i)*64 + qb]      * a0;
          mv[1][i] += *(const f32x4*)&q5T[(u*3+i)*64 + 16 + qb] * a1;
          mv[2][i] += *(const f32x4*)&q5T[(u*3+i)*64 + 32 + qb] * a2;
          mv[3][i] += *(const f32x4*)&q5T[(u*3+i)*64 + 48 + qb] * a3;
        }
      }
    }
    __syncthreads();
    __syncthreads();
    #pragma unroll
    for (int g = 0; g < 4; ++g) {
      #pragma unroll
      for (int r = 0; r < 4; ++r) {
        const int eb = g*16 + qb + r;
        float* mp = msg + (size_t)eposS[eb]*96;
        #pragma unroll
        for (int i = 0; i < 3; ++i)
          mp[48 + 3*L + i] = (mv[g][i][r] + poolC[eb*48 + i*16 + L]) * S64;
      }
    }
  }
#undef GCORE
#undef PRIME
}

// ---------------- fused: CSR-streaming gather + node update + next node linears / proj --
// 8 nodes/block (768 gather items = 3 full 256-thread passes, full lane utilization)
// + 4-way unrolled accumulators over the contiguous CSR msg stream.
__global__ void agg_fused_kernel(const float* __restrict__ msg, const int* __restrict__ offs,
                                 const float* __restrict__ xself_in, float* __restrict__ h,
                                 const float* __restrict__ lwsN, const float* __restrict__ lwvN,
                                 const float* __restrict__ swsN, const float* __restrict__ swvN,
                                 float* __restrict__ hx_out, float* __restrict__ xself_out,
                                 const float* __restrict__ pw, float* __restrict__ out,
                                 int last) {
  __shared__ float sagg[8][96];
  __shared__ float hnew[8][80];
  int t = threadIdx.x;
  int nb = blockIdx.x * 8;
  for (int idx = t; idx < 8*96; idx += 256) {
    int nl = idx / 96, c = idx % 96;
    int n = nb + nl;
    int b = offs[n], e = offs[n+1];
    float a0 = 0.0f, a1 = 0.0f, a2 = 0.0f, a3 = 0.0f;
    int j = b;
    for (; j + 3 < e; j += 4) {
      a0 += msg[(size_t)j*96 + c];
      a1 += msg[(size_t)(j+1)*96 + c];
      a2 += msg[(size_t)(j+2)*96 + c];
      a3 += msg[(size_t)(j+3)*96 + c];
    }
    for (; j < e; ++j) a0 += msg[(size_t)j*96 + c];
    sagg[nl][c] = ((a0 + a1) + (a2 + a3)) * 0.20412414523193154f;   // 1/sqrt(24)
  }
  __syncthreads();
  for (int idx = t; idx < 8*80; idx += 256) {
    int nl = idx / 80, c = idx % 80;
    int n = nb + nl;
    float a;
    if (c < 32) {
      a = silu_f(sagg[nl][c]);
    } else {
      int oc = c - 32, wch = oc / 3;
      a = sagg[nl][48 + oc] * sigm_f(sagg[nl][32 + wch]);
    }
    float hn = h[(size_t)n*80 + c] + xself_in[(size_t)n*80 + c] + a;
    hnew[nl][c] = hn;
    h[(size_t)n*80 + c] = hn;
  }
  __syncthreads();
  if (!last) {
    for (int idx = t; idx < 2*8*80; idx += 256) {
      int which = idx / 640, r = idx % 640;
      int nl = r / 80, c = r % 80;
      int n = nb + nl;
      const float* Ws = which ? swsN : lwsN;
      const float* Wv = which ? swvN : lwvN;
      float v = 0.0f;
      if (c < 32) {
        #pragma unroll 8
        for (int u = 0; u < 32; u++) v += hnew[nl][u] * Ws[u*32 + c];
        v *= 0.17677669529663687f;
      } else {
        int oc = c - 32, wch = oc / 3, i = oc % 3;
        #pragma unroll
        for (int u = 0; u < 16; u++) v += hnew[nl][32 + u*3 + i] * Wv[u*16 + wch];
        v *= 0.25f;
      }
      (which ? xself_out : hx_out)[(size_t)n*80 + c] = v;
    }
  } else {
    for (int idx = t; idx < 8*32; idx += 256) {
      int nl = idx / 32, c = idx % 32;
      int n = nb + nl;
      float acc = 0.0f;
      #pragma unroll 8
      for (int u = 0; u < 32; u++) acc += hnew[nl][u] * pw[u*32 + c];
      out[(size_t)n*32 + c] = acc * 0.17677669529663687f;
    }
  }
}

extern "C" void kernel_launch(void* const* d_in, const int* in_sizes, int n_in,
                              void* d_out, int out_size, void* d_ws, size_t ws_size,
                              hipStream_t stream) {
  const float* x       = (const float*)d_in[0];
  const float* pos     = (const float*)d_in[1];
  const int*   ei      = (const int*)  d_in[2];
  const float* embed_w = (const float*)d_in[3];
  const float* proj_w  = (const float*)d_in[4];
  const float* lin_ws  = (const float*)d_in[5];
  const float* lin_wv  = (const float*)d_in[6];
  const float* sc_ws   = (const float*)d_in[7];
  const float* sc_wv   = (const float*)d_in[8];
  const float* mlp_w1  = (const float*)d_in[9];
  const float* mlp_b1  = (const float*)d_in[10];
  const float* mlp_w2  = (const float*)d_in[11];
  const float* mlp_b2  = (const float*)d_in[12];
  const float* mlp_w3  = (const float*)d_in[13];
  const float* mlp_b3  = (const float*)d_in[14];
  float* out = (float*)d_out;

  float* ws    = (float*)d_ws;
  float* egeo  = ws;                          // NE*20
  float* h     = egeo  + (size_t)NE*20;       // NN*80
  float* hx    = h     + (size_t)NN*80;       // NN*80
  float* xself = hx    + (size_t)NN*80;       // NN*80
  float* msg   = xself + (size_t)NN*80;       // NE*96 (CSR-ordered rows)
  _Float16* f_h = (_Float16*)(msg + (size_t)NE*96);   // 4*NE*64 f16 (all layers)
  _Float16* w3h = f_h + (size_t)4*NE*64;              // 4*208*1024 f16
  int* cnt    = (int*)(w3h + (size_t)4*208*1024);     // NN
  int* offs   = cnt + NN;                     // NN+1
  int* cursor = offs + NN + 1;                // NN
  int* epos   = cursor + NN;                  // NE

  hipMemsetAsync(cnt, 0, NN*sizeof(int), stream);
  geom_kernel<<<(NE + 255)/256, 256, 0, stream>>>(pos, ei, egeo, cnt);
  scan_kernel<<<1, 256, 0, stream>>>(cnt, offs, cursor);
  scatter_kernel<<<NE/256, 256, 0, stream>>>(ei, cursor, epos);
  conv_w3_kernel<<<(16*WNUM + 255)/256, 256, 0, stream>>>(mlp_w3, w3h);
  radial_all_kernel<<<NBR1*4, 256, 0, stream>>>(egeo, mlp_w1, mlp_b1, mlp_w2, mlp_b2, f_h);
  embed_prep_kernel<<<NN/8, 256, 0, stream>>>(x, embed_w, lin_ws, sc_ws, h, hx, xself);

  for (int l = 0; l < 4; l++) {
    edge_msg_kernel<<<NE/64, 256, 0, stream>>>(ei, egeo, f_h + (size_t)l*NE*64, hx,
                                               w3h, mlp_b3, epos, msg, l);
    int last = (l == 3);
    agg_fused_kernel<<<NN/8, 256, 0, stream>>>(
        msg, offs, xself, h,
        lin_ws + (size_t)(l+1 < 4 ? l+1 : 0) * 1024,
        lin_wv + (size_t)(l+1 < 4 ? l+1 : 0) * 256,
        sc_ws  + (size_t)(l+1 < 4 ? l+1 : 0) * 1024,
        sc_wv  + (size_t)(l+1 < 4 ? l+1 : 0) * 256,
        hx, xself, proj_w, out, last);
  }
}

// Round 19
// 448.219 us; speedup vs baseline: 1.4822x; 1.0349x over previous
//
#include <hip/hip_runtime.h>
#include <math.h>

#define NN 2048
#define NE 49152
#define WNUM 3328

typedef __attribute__((ext_vector_type(8))) _Float16 half8;
typedef __attribute__((ext_vector_type(4))) float f32x4;

__device__ __forceinline__ float silu_f(float x){ return x / (1.0f + expf(-x)); }
__device__ __forceinline__ float sigm_f(float x){ return 1.0f / (1.0f + expf(-x)); }

// ---------------- edge geometry: y1(3), Ay(9), rbf(8) -> egeo stride 20; + dst histogram ----
__global__ void geom_kernel(const float* __restrict__ pos, const int* __restrict__ ei,
                            float* __restrict__ egeo, int* __restrict__ cnt) {
  int e = blockIdx.x * 256 + threadIdx.x;
  if (e >= NE) return;
  int s = ei[e], d = ei[NE + e];
  atomicAdd(&cnt[d], 1);
  float rx = pos[d*3+0] - pos[s*3+0];
  float ry = pos[d*3+1] - pos[s*3+1];
  float rz = pos[d*3+2] - pos[s*3+2];
  float r = sqrtf(rx*rx + ry*ry + rz*rz);
  r = fmaxf(r, 1e-6f);
  float x = rx / r, y = ry / r, z = rz / r;
  const float s3 = 1.7320508075688772f;
  const float c15 = 3.872983346207417f;
  float y2_0 = c15 * x * y;
  float y2_1 = c15 * y * z;
  float y2_2 = 1.118033988749895f * (3.0f*z*z - 1.0f);
  float y2_3 = c15 * x * z;
  float y2_4 = 1.9364916731037085f * (x*x - y*y);
  const float q2 = 0.7071067811865476f;
  const float q6 = 0.4082482904638631f;
  float* g = egeo + (size_t)e * 20;
  g[0] = s3 * x; g[1] = s3 * y; g[2] = s3 * z;
  g[3+0] = -q6*y2_2 + q2*y2_4;
  g[3+1] =  q2*y2_0;
  g[3+2] =  q2*y2_3;
  g[3+3] =  q2*y2_0;
  g[3+4] = -q6*y2_2 - q2*y2_4;
  g[3+5] =  q2*y2_1;
  g[3+6] =  q2*y2_3;
  g[3+7] =  q2*y2_1;
  g[3+8] =  2.0f*q6*y2_2;
  float u = r / 6.0f;
  float fc = 0.0f;
  if (u < 1.0f) {
    float u2=u*u, u3=u2*u, u6=u3*u3, u7=u6*u, u8=u7*u;
    fc = 1.0f - 28.0f*u6 + 48.0f*u7 - 21.0f*u8;
  }
  const float pref = 0.5773502691896258f;
  const float pi6 = 0.5235987755982988f;
  #pragma unroll
  for (int n = 1; n <= 8; n++) {
    g[12 + n - 1] = pref * sinf((float)n * pi6 * r) / r * fc;
  }
}

// ---------------- CSR scan ----------------
__global__ void scan_kernel(const int* __restrict__ cnt, int* __restrict__ offs,
                            int* __restrict__ cursor) {
  __shared__ int part[256];
  int t = threadIdx.x;
  int local[8];
  int s = 0;
  #pragma unroll
  for (int j = 0; j < 8; j++) { local[j] = s; s += cnt[t*8 + j]; }
  part[t] = s;
  __syncthreads();
  for (int off = 1; off < 256; off <<= 1) {
    int v = part[t];
    int add = (t >= off) ? part[t - off] : 0;
    __syncthreads();
    part[t] = v + add;
    __syncthreads();
  }
  int excl = (t == 0) ? 0 : part[t-1];
  #pragma unroll
  for (int j = 0; j < 8; j++) {
    int o = excl + local[j];
    offs[t*8 + j] = o;
    cursor[t*8 + j] = o;
  }
  if (t == 255) offs[2048] = part[255];
}

// scatter: record each edge's CSR slot (epos) so edge_msg can write msg in CSR order
__global__ void scatter_kernel(const int* __restrict__ ei, int* __restrict__ cursor,
                               int* __restrict__ epos) {
  int e = blockIdx.x * 256 + threadIdx.x;
  if (e >= NE) return;
  int d = ei[NE + e];
  int p = atomicAdd(&cursor[d], 1);
  epos[e] = p;
}

// ---------------- W3 -> f16, MFMA-B-fragment-ordered ----------------
__global__ void conv_w3_kernel(const float* __restrict__ w3g, _Float16* __restrict__ w3h) {
  int tid = blockIdx.x * 256 + threadIdx.x;
  if (tid >= 16 * WNUM) return;
  int n = tid % WNUM;
  int lq = tid / WNUM;           // l*4 + quad
  int quad = lq & 3, l = lq >> 2;
  const float* src = w3g + (size_t)l * 64 * WNUM + n;
  int idx = n >> 4, L = n & 15;
  _Float16* dst = w3h + ((size_t)(l * 208 + idx) * 2) * 512 + (quad*16 + L) * 8;
  half8 h0, h1;
  #pragma unroll
  for (int j = 0; j < 8; j++) {
    h0[j] = (_Float16)src[(size_t)(quad*8 + j) * WNUM];
    h1[j] = (_Float16)src[(size_t)(32 + quad*8 + j) * WNUM];
  }
  *(half8*)(dst)       = h0;
  *(half8*)(dst + 512) = h1;
}

// ---------------- W2 -> f16, MFMA-B-fragment-ordered (for radial MFMA) ----------------
// w2h[((l*4 + ct)*2 + plane)*512 + (quad*16+Lc)*8 + j] = W2[l][k][n],
//   k = plane*32 + quad*8 + j, n = ct*16 + Lc
__global__ void conv_w2_kernel(const float* __restrict__ w2g, _Float16* __restrict__ w2h) {
  int tid = blockIdx.x * 256 + threadIdx.x;
  if (tid >= 16384) return;
  int j = tid & 7, lane = (tid >> 3) & 63, plane = (tid >> 9) & 1;
  int ct = (tid >> 10) & 3, l = tid >> 12;
  int q = lane >> 4, Lc = lane & 15;
  int k = plane*32 + q*8 + j;
  int n = ct*16 + Lc;
  w2h[tid] = (_Float16)w2g[(size_t)l*4096 + k*64 + n];
}

// ---------------- radial MLP via MFMA: f = silu(silu(rbf@W1+b1)@W2+b2) -> f16 ----
// 64 edges/block, grid = 4 layers x NE/64. Stage 1 fp32 VALU (tiny 8xK GEMM) ->
// h1 f16 in LDS (72-pad rows, 2-way-free bank pattern). Stage 2: 2 MFMAs per
// 16x16 output tile (K=64), bias as accumulator seed, silu epilogue, f16 store
// in edge_msg's A-fragment row-major layout.
__global__ void radial_mfma_kernel(const float* __restrict__ egeo,
                                   const float* __restrict__ w1, const float* __restrict__ b1,
                                   const float* __restrict__ b2,
                                   const _Float16* __restrict__ w2h,
                                   _Float16* __restrict__ f_h) {
  __shared__ _Float16 h1s[64*72];
  const int t = threadIdx.x;
  const int l = blockIdx.x / (NE/64);
  const int e0 = (blockIdx.x % (NE/64)) * 64;
  const float* w1l = w1 + (size_t)l * 512;
  _Float16* fl = f_h + (size_t)l * NE * 64;

  // ---- stage 1: h1 = silu(rbf @ W1 + b1), 16 outputs/thread ----
  {
    int e = t >> 2, jb = (t & 3) * 16;
    const float* rb = egeo + (size_t)(e0 + e) * 20 + 12;
    float r0 = rb[0], r1 = rb[1], r2 = rb[2], r3 = rb[3];
    float r4 = rb[4], r5 = rb[5], r6 = rb[6], r7 = rb[7];
    #pragma unroll
    for (int jj = 0; jj < 16; ++jj) {
      int j = jb + jj;
      float acc = b1[l*64 + j];
      acc += r0 * w1l[0*64 + j];
      acc += r1 * w1l[1*64 + j];
      acc += r2 * w1l[2*64 + j];
      acc += r3 * w1l[3*64 + j];
      acc += r4 * w1l[4*64 + j];
      acc += r5 * w1l[5*64 + j];
      acc += r6 * w1l[6*64 + j];
      acc += r7 * w1l[7*64 + j];
      h1s[e*72 + j] = (_Float16)silu_f(acc);
    }
  }
  __syncthreads();

  // ---- stage 2: f = silu(h1 @ W2 + b2) via MFMA ----
  const int wv = t >> 6, lane = t & 63, L = lane & 15, quad = lane >> 4;
  half8 A0 = *(const half8*)&h1s[(wv*16 + L)*72 + quad*8];
  half8 A1 = *(const half8*)&h1s[(wv*16 + L)*72 + 32 + quad*8];
  #pragma unroll
  for (int ct = 0; ct < 4; ++ct) {
    const _Float16* wB = w2h + ((size_t)(l*4 + ct) * 2) * 512 + lane*8;
    half8 B0 = *(const half8*)(wB);
    half8 B1 = *(const half8*)(wB + 512);
    float bb = b2[l*64 + ct*16 + L];
    f32x4 acc = {bb, bb, bb, bb};
    acc = __builtin_amdgcn_mfma_f32_16x16x32_f16(A0, B0, acc, 0, 0, 0);
    acc = __builtin_amdgcn_mfma_f32_16x16x32_f16(A1, B1, acc, 0, 0, 0);
    #pragma unroll
    for (int r = 0; r < 4; ++r) {
      fl[(size_t)(e0 + wv*16 + quad*4 + r)*64 + ct*16 + L] = (_Float16)silu_f(acc[r]);
    }
  }
}

// ---------------- embed + layer-0 node linears (h v-part = 0 => hx/xself v-part = 0) ---
__global__ void embed_prep_kernel(const float* __restrict__ x, const float* __restrict__ ew,
                                  const float* __restrict__ lws0, const float* __restrict__ sws0,
                                  float* __restrict__ h, float* __restrict__ hx,
                                  float* __restrict__ xself) {
  __shared__ float hs[8][32];
  int t = threadIdx.x;
  int nl = t >> 5, c = t & 31;
  int n = blockIdx.x * 8 + nl;
  float v = 0.0f;
  #pragma unroll
  for (int j = 0; j < 16; j++) v += x[n*16 + j] * ew[j*32 + c];
  v *= 0.25f;
  hs[nl][c] = v;
  h[(size_t)n*80 + c] = v;
  for (int idx = t; idx < 8*48; idx += 256) {
    int nn = blockIdx.x * 8 + idx / 48;
    h[(size_t)nn*80 + 32 + idx % 48] = 0.0f;
  }
  __syncthreads();
  for (int idx = t; idx < 2*8*80; idx += 256) {
    int which = idx / 640, r = idx % 640;
    int nl2 = r / 80, cc = r % 80;
    int n2 = blockIdx.x * 8 + nl2;
    float o = 0.0f;
    if (cc < 32) {
      const float* W = which ? sws0 : lws0;
      #pragma unroll 8
      for (int u = 0; u < 32; u++) o += hs[nl2][u] * W[u*32 + cc];
      o *= 0.17677669529663687f;
    }
    (which ? xself : hx)[(size_t)n2*80 + cc] = o;
  }
}

// ---------------- fused MFMA weight-GEMM (f16) + tensor product -> msg (CSR order) ----
// R16-EXACT — FROZEN. 457 us total, edge_msg 65 us/layer, VGPR 116, no spill.
// Evidence (R15, R17): ANY restructuring of the K-loop branches tips the register
// allocator over the 128-VGPR cliff -> 3-6x scratch-spill regression. Do not touch.
__launch_bounds__(256, 2)
__global__ void edge_msg_kernel(const int* __restrict__ ei, const float* __restrict__ egeo,
                                const _Float16* __restrict__ f_h,
                                const float* __restrict__ hx,
                                const _Float16* __restrict__ w3h,
                                const float* __restrict__ b3g,
                                const int* __restrict__ epos,
                                float* __restrict__ msg, int l) {
  __shared__ float smem[15616];            // 62.5 KB
  __shared__ int eposS[64];
  float* sT    = smem;                     // [32][64]
  float* p2T   = smem + 2048;              // [16][64]
  float* q3T   = smem + 3072;              // [48][64]  s_u * y1_i
  float* vT    = smem + 6144;              // [48][64]
  float* q5T   = smem + 9216;              // [48][64]
  float* biasL = smem + 12288;             // [3328]
  float* poolA = smem;                     // post-loop overlay (sT+p2T dead)
  float* poolB = smem + 3072;              // overlay (q3T dead)
  float* poolC = smem + 6144;              // overlay (vT dead)

  const int t = threadIdx.x;
  const int e0 = blockIdx.x * 64;
  const float* b3l = b3g + (size_t)l * WNUM;

  // ---- prologue ----
  for (int i = t; i < WNUM; i += 256) biasL[i] = b3l[i];
  if (t < 64) eposS[t] = epos[e0 + t];
  for (int idx = t; idx < 64*80; idx += 256) {
    int e = idx / 80, c = idx % 80;
    int src = ei[e0 + e];
    float val = hx[(size_t)src*80 + c];
    if (c < 32) sT[c*64 + e] = val; else vT[(c-32)*64 + e] = val;
  }
  __syncthreads();
  for (int idx = t; idx < 64*16; idx += 256) {
    int u = idx >> 6, e = idx & 63;
    const float* g = &egeo[(size_t)(e0+e)*20];
    float a = vT[(u*3)*64+e]*g[0] + vT[(u*3+1)*64+e]*g[1] + vT[(u*3+2)*64+e]*g[2];
    p2T[u*64 + e] = a * 0.5773502691896258f;
  }
  for (int idx = t; idx < 64*48; idx += 256) {
    int o = idx >> 6, e = idx & 63;
    int u = o / 3, jj = o % 3;
    const float* g = &egeo[(size_t)(e0+e)*20];
    q3T[o*64 + e] = sT[u*64 + e] * g[jj];
    float a = vT[(u*3)*64+e]*g[3+jj] + vT[(u*3+1)*64+e]*g[6+jj] + vT[(u*3+2)*64+e]*g[9+jj];
    q5T[o*64 + e] = a * 0.7745966692414834f;
  }

  const int wv = t >> 6, lane = t & 63, L = lane & 15, quad = lane >> 4;
  const int qb = quad * 4;

  // A fragments for all 4 edge-groups (32 VGPR)
  half8 Ah[4][2];
  #pragma unroll
  for (int g = 0; g < 4; ++g) {
    const half8* fA = (const half8*)(f_h + (size_t)(e0 + g*16 + L)*64);
    Ah[g][0] = fA[quad];
    Ah[g][1] = fA[4 + quad];
  }
  __syncthreads();   // LDS (factors + bias + epos) ready

  const _Float16* wb = w3h + (size_t)l * 208 * 1024 + lane * 8;
  half8 pb0[4], pb1[4];
  float bs[4];

#define PRIME(START)                                                          \
  { _Pragma("unroll")                                                         \
    for (int _s = 0; _s < 4; ++_s) {                                          \
      const _Float16* _wn = wb + (size_t)((START) + _s) * 1024;               \
      pb0[_s] = *(const half8*)_wn;                                           \
      pb1[_s] = *(const half8*)(_wn + 512);                                   \
      bs[_s] = biasL[((START) + _s)*16 + L];                                  \
    } }

  // declares a0..a3 (one per edge-group); CO compile-time
#define GCORE(IDX, CO, OKCOND)                                                \
  f32x4 a0, a1, a2, a3;                                                       \
  { half8 _B0 = pb0[(CO)&3], _B1 = pb1[(CO)&3];                               \
    float _bb = bs[(CO)&3];                                                   \
    if (OKCOND) {                                                             \
      const _Float16* _wn = wb + (size_t)((IDX) + 4) * 1024;                  \
      pb0[(CO)&3] = *(const half8*)_wn;                                       \
      pb1[(CO)&3] = *(const half8*)(_wn + 512);                               \
      bs[(CO)&3] = biasL[((IDX) + 4)*16 + L];                                 \
    }                                                                         \
    a0 = (f32x4){_bb,_bb,_bb,_bb}; a1 = a0; a2 = a0; a3 = a0;                 \
    a0 = __builtin_amdgcn_mfma_f32_16x16x32_f16(Ah[0][0], _B0, a0, 0,0,0);    \
    a0 = __builtin_amdgcn_mfma_f32_16x16x32_f16(Ah[0][1], _B1, a0, 0,0,0);    \
    a1 = __builtin_amdgcn_mfma_f32_16x16x32_f16(Ah[1][0], _B0, a1, 0,0,0);    \
    a1 = __builtin_amdgcn_mfma_f32_16x16x32_f16(Ah[1][1], _B1, a1, 0,0,0);    \
    a2 = __builtin_amdgcn_mfma_f32_16x16x32_f16(Ah[2][0], _B0, a2, 0,0,0);    \
    a2 = __builtin_amdgcn_mfma_f32_16x16x32_f16(Ah[2][1], _B1, a2, 0,0,0);    \
    a3 = __builtin_amdgcn_mfma_f32_16x16x32_f16(Ah[3][0], _B0, a3, 0,0,0);    \
    a3 = __builtin_amdgcn_mfma_f32_16x16x32_f16(Ah[3][1], _B1, a3, 0,0,0);    \
  }

  const float S48 = 0.14433756729740645f;  // 1/sqrt(48)
  const float S64 = 0.125f;                // 1/sqrt(64)

  if (wv <= 1) {
    f32x4 ms[4][3];
    #pragma unroll
    for (int g = 0; g < 4; ++g)
      #pragma unroll
      for (int j = 0; j < 3; ++j) ms[g][j] = (f32x4){0,0,0,0};
    const int ustart = wv * 16, istart = wv * 48, iend = istart + 48;
    PRIME(istart);
    for (int u4 = 0; u4 < 16; u4 += 4) {
      #pragma unroll
      for (int uu = 0; uu < 4; ++uu) {
        const int u = u4 + uu;
        f32x4 f0 = *(const f32x4*)&sT[(ustart+u)*64 + qb];
        f32x4 f1 = *(const f32x4*)&sT[(ustart+u)*64 + 16 + qb];
        f32x4 f2 = *(const f32x4*)&sT[(ustart+u)*64 + 32 + qb];
        f32x4 f3 = *(const f32x4*)&sT[(ustart+u)*64 + 48 + qb];
        #pragma unroll
        for (int j = 0; j < 3; ++j) {
          const int CO = uu*3 + j;
          const int idx = istart + u4*3 + CO;
          GCORE(idx, CO, idx + 4 < iend);
          ms[0][j] += f0*a0; ms[1][j] += f1*a1; ms[2][j] += f2*a2; ms[3][j] += f3*a3;
        }
      }
    }
    float* pool = (wv == 0) ? poolA : poolB;
    __syncthreads();
    #pragma unroll
    for (int g = 0; g < 4; ++g)
      #pragma unroll
      for (int j = 0; j < 3; ++j)
        #pragma unroll
        for (int r = 0; r < 4; ++r)
          pool[(g*16 + qb + r)*48 + j*16 + L] = ms[g][j][r];
    __syncthreads();
  } else if (wv == 2) {
    f32x4 ms[4][3], mv[4][3];
    #pragma unroll
    for (int g = 0; g < 4; ++g)
      #pragma unroll
      for (int j = 0; j < 3; ++j) { ms[g][j] = (f32x4){0,0,0,0}; mv[g][j] = (f32x4){0,0,0,0}; }
    PRIME(96);
    for (int u4 = 0; u4 < 16; u4 += 4) {
      #pragma unroll
      for (int uu = 0; uu < 4; ++uu) {
        const int u = u4 + uu;
        f32x4 f0 = *(const f32x4*)&p2T[u*64 + qb];
        f32x4 f1 = *(const f32x4*)&p2T[u*64 + 16 + qb];
        f32x4 f2 = *(const f32x4*)&p2T[u*64 + 32 + qb];
        f32x4 f3 = *(const f32x4*)&p2T[u*64 + 48 + qb];
        #pragma unroll
        for (int j = 0; j < 3; ++j) {
          const int CO = uu*3 + j;
          const int idx = 96 + u4*3 + CO;
          GCORE(idx, CO, idx + 4 < 144);
          ms[0][j] += f0*a0; ms[1][j] += f1*a1; ms[2][j] += f2*a2; ms[3][j] += f3*a3;
        }
      }
    }
    PRIME(176);
    for (int u4 = 0; u4 < 16; u4 += 4) {
      #pragma unroll
      for (int uu = 0; uu < 4; ++uu) {
        const int u = u4 + uu;
        const int idx = 176 + u;
        GCORE(idx, uu, idx + 4 < 192);
        #pragma unroll
        for (int i = 0; i < 3; ++i) {
          mv[0][i] += *(const f32x4*)&vT[(u*3+i)*64 + qb]      * a0;
          mv[1][i] += *(const f32x4*)&vT[(u*3+i)*64 + 16 + qb] * a1;
          mv[2][i] += *(const f32x4*)&vT[(u*3+i)*64 + 32 + qb] * a2;
          mv[3][i] += *(const f32x4*)&vT[(u*3+i)*64 + 48 + qb] * a3;
        }
      }
    }
    __syncthreads();
    #pragma unroll
    for (int g = 0; g < 4; ++g)
      #pragma unroll
      for (int i = 0; i < 3; ++i)
        #pragma unroll
        for (int r = 0; r < 4; ++r)
          poolC[(g*16 + qb + r)*48 + i*16 + L] = mv[g][i][r];
    __syncthreads();
    #pragma unroll
    for (int g = 0; g < 4; ++g) {
      #pragma unroll
      for (int r = 0; r < 4; ++r) {
        const int eb = g*16 + qb + r;
        float* mp = msg + (size_t)eposS[eb]*96;
        #pragma unroll
        for (int j = 0; j < 3; ++j)
          mp[j*16 + L] = (ms[g][j][r] + poolA[eb*48 + j*16 + L] + poolB[eb*48 + j*16 + L]) * S48;
      }
    }
  } else {
    f32x4 mv[4][3];
    #pragma unroll
    for (int g = 0; g < 4; ++g)
      #pragma unroll
      for (int i = 0; i < 3; ++i) mv[g][i] = (f32x4){0,0,0,0};
    PRIME(144);
    for (int u4 = 0; u4 < 32; u4 += 4) {
      #pragma unroll
      for (int uu = 0; uu < 4; ++uu) {
        const int u = u4 + uu;
        const int idx = 144 + u;
        GCORE(idx, uu, idx + 4 < 176);
        #pragma unroll
        for (int i = 0; i < 3; ++i) {
          mv[0][i] += *(const f32x4*)&q3T[(u*3+i)*64 + qb]      * a0;
          mv[1][i] += *(const f32x4*)&q3T[(u*3+i)*64 + 16 + qb] * a1;
          mv[2][i] += *(const f32x4*)&q3T[(u*3+i)*64 + 32 + qb] * a2;
          mv[3][i] += *(const f32x4*)&q3T[(u*3+i)*64 + 48 + qb] * a3;
        }
      }
    }
    PRIME(192);
    for (int u4 = 0; u4 < 16; u4 += 4) {
      #pragma unroll
      for (int uu = 0; uu < 4; ++uu) {
        const int u = u4 + uu;
        const int idx = 192 + u;
        GCORE(idx, uu, idx + 4 < 208);
        #pragma unroll
        for (int i = 0; i < 3; ++i) {
          mv[0][i] += *(const f32x4*)&q5T[(u*3+i)*64 + qb]      * a0;
          mv[1][i] += *(const f32x4*)&q5T[(u*3+i)*64 + 16 + qb] * a1;
          mv[2][i] += *(const f32x4*)&q5T[(u*3+i)*64 + 32 + qb] * a2;
          mv[3][i] += *(const f32x4*)&q5T[(u*3+i)*64 + 48 + qb] * a3;
        }
      }
    }
    __syncthreads();
    __syncthreads();
    #pragma unroll
    for (int g = 0; g < 4; ++g) {
      #pragma unroll
      for (int r = 0; r < 4; ++r) {
        const int eb = g*16 + qb + r;
        float* mp = msg + (size_t)eposS[eb]*96;
        #pragma unroll
        for (int i = 0; i < 3; ++i)
          mp[48 + 3*L + i] = (mv[g][i][r] + poolC[eb*48 + i*16 + L]) * S64;
      }
    }
  }
#undef GCORE
#undef PRIME
}

// ---------------- fused: CSR-streaming gather + node update + next node linears / proj --
// R16 version (4 nodes/block) — best measured total.
__global__ void agg_fused_kernel(const float* __restrict__ msg, const int* __restrict__ offs,
                                 const float* __restrict__ xself_in, float* __restrict__ h,
                                 const float* __restrict__ lwsN, const float* __restrict__ lwvN,
                                 const float* __restrict__ swsN, const float* __restrict__ swvN,
                                 float* __restrict__ hx_out, float* __restrict__ xself_out,
                                 const float* __restrict__ pw, float* __restrict__ out,
                                 int last) {
  __shared__ float sagg[4][96];
  __shared__ float hnew[4][80];
  int t = threadIdx.x;
  int nb = blockIdx.x * 4;
  for (int idx = t; idx < 4*96; idx += 256) {
    int nl = idx / 96, c = idx % 96;
    int n = nb + nl;
    int b = offs[n], e = offs[n+1];
    float acc = 0.0f, acc2 = 0.0f;
    int j = b;
    for (; j + 1 < e; j += 2) {
      acc  += msg[(size_t)j*96 + c];
      acc2 += msg[(size_t)(j+1)*96 + c];
    }
    if (j < e) acc += msg[(size_t)j*96 + c];
    sagg[nl][c] = (acc + acc2) * 0.20412414523193154f;   // 1/sqrt(24)
  }
  __syncthreads();
  for (int idx = t; idx < 4*80; idx += 256) {
    int nl = idx / 80, c = idx % 80;
    int n = nb + nl;
    float a;
    if (c < 32) {
      a = silu_f(sagg[nl][c]);
    } else {
      int oc = c - 32, wch = oc / 3;
      a = sagg[nl][48 + oc] * sigm_f(sagg[nl][32 + wch]);
    }
    float hn = h[(size_t)n*80 + c] + xself_in[(size_t)n*80 + c] + a;
    hnew[nl][c] = hn;
    h[(size_t)n*80 + c] = hn;
  }
  __syncthreads();
  if (!last) {
    for (int idx = t; idx < 2*4*80; idx += 256) {
      int which = idx / 320, r = idx % 320;
      int nl = r / 80, c = r % 80;
      int n = nb + nl;
      const float* Ws = which ? swsN : lwsN;
      const float* Wv = which ? swvN : lwvN;
      float v = 0.0f;
      if (c < 32) {
        #pragma unroll 8
        for (int u = 0; u < 32; u++) v += hnew[nl][u] * Ws[u*32 + c];
        v *= 0.17677669529663687f;
      } else {
        int oc = c - 32, wch = oc / 3, i = oc % 3;
        #pragma unroll
        for (int u = 0; u < 16; u++) v += hnew[nl][32 + u*3 + i] * Wv[u*16 + wch];
        v *= 0.25f;
      }
      (which ? xself_out : hx_out)[(size_t)n*80 + c] = v;
    }
  } else {
    for (int idx = t; idx < 4*32; idx += 256) {
      int nl = idx / 32, c = idx % 32;
      int n = nb + nl;
      float acc = 0.0f;
      #pragma unroll 8
      for (int u = 0; u < 32; u++) acc += hnew[nl][u] * pw[u*32 + c];
      out[(size_t)n*32 + c] = acc * 0.17677669529663687f;
    }
  }
}

extern "C" void kernel_launch(void* const* d_in, const int* in_sizes, int n_in,
                              void* d_out, int out_size, void* d_ws, size_t ws_size,
                              hipStream_t stream) {
  const float* x       = (const float*)d_in[0];
  const float* pos     = (const float*)d_in[1];
  const int*   ei      = (const int*)  d_in[2];
  const float* embed_w = (const float*)d_in[3];
  const float* proj_w  = (const float*)d_in[4];
  const float* lin_ws  = (const float*)d_in[5];
  const float* lin_wv  = (const float*)d_in[6];
  const float* sc_ws   = (const float*)d_in[7];
  const float* sc_wv   = (const float*)d_in[8];
  const float* mlp_w1  = (const float*)d_in[9];
  const float* mlp_b1  = (const float*)d_in[10];
  const float* mlp_w2  = (const float*)d_in[11];
  const float* mlp_b2  = (const float*)d_in[12];
  const float* mlp_w3  = (const float*)d_in[13];
  const float* mlp_b3  = (const float*)d_in[14];
  float* out = (float*)d_out;

  float* ws    = (float*)d_ws;
  float* egeo  = ws;                          // NE*20
  float* h     = egeo  + (size_t)NE*20;       // NN*80
  float* hx    = h     + (size_t)NN*80;       // NN*80
  float* xself = hx    + (size_t)NN*80;       // NN*80
  float* msg   = xself + (size_t)NN*80;       // NE*96 (CSR-ordered rows)
  _Float16* f_h = (_Float16*)(msg + (size_t)NE*96);   // 4*NE*64 f16 (all layers)
  _Float16* w3h = f_h + (size_t)4*NE*64;              // 4*208*1024 f16
  _Float16* w2h = w3h + (size_t)4*208*1024;           // 16384 f16 (32 KB)
  int* cnt    = (int*)(w2h + 16384);          // NN
  int* offs   = cnt + NN;                     // NN+1
  int* cursor = offs + NN + 1;                // NN
  int* epos   = cursor + NN;                  // NE

  hipMemsetAsync(cnt, 0, NN*sizeof(int), stream);
  geom_kernel<<<(NE + 255)/256, 256, 0, stream>>>(pos, ei, egeo, cnt);
  scan_kernel<<<1, 256, 0, stream>>>(cnt, offs, cursor);
  scatter_kernel<<<NE/256, 256, 0, stream>>>(ei, cursor, epos);
  conv_w3_kernel<<<(16*WNUM + 255)/256, 256, 0, stream>>>(mlp_w3, w3h);
  conv_w2_kernel<<<64, 256, 0, stream>>>(mlp_w2, w2h);
  radial_mfma_kernel<<<4*(NE/64), 256, 0, stream>>>(egeo, mlp_w1, mlp_b1, mlp_b2, w2h, f_h);
  embed_prep_kernel<<<NN/8, 256, 0, stream>>>(x, embed_w, lin_ws, sc_ws, h, hx, xself);

  for (int l = 0; l < 4; l++) {
    edge_msg_kernel<<<NE/64, 256, 0, stream>>>(ei, egeo, f_h + (size_t)l*NE*64, hx,
                                               w3h, mlp_b3, epos, msg, l);
    int last = (l == 3);
    agg_fused_kernel<<<NN/4, 256, 0, stream>>>(
        msg, offs, xself, h,
        lin_ws + (size_t)(l+1 < 4 ? l+1 : 0) * 1024,
        lin_wv + (size_t)(l+1 < 4 ? l+1 : 0) * 256,
        sc_ws  + (size_t)(l+1 < 4 ? l+1 : 0) * 1024,
        sc_wv  + (size_t)(l+1 < 4 ? l+1 : 0) * 256,
        hx, xself, proj_w, out, last);
  }
}

// Round 20
// 443.582 us; speedup vs baseline: 1.4977x; 1.0105x over previous
//
#include <hip/hip_runtime.h>
#include <math.h>

#define NN 2048
#define NE 49152
#define WNUM 3328

typedef __attribute__((ext_vector_type(8))) _Float16 half8;
typedef __attribute__((ext_vector_type(4))) float f32x4;

__device__ __forceinline__ float silu_f(float x){ return x / (1.0f + expf(-x)); }
__device__ __forceinline__ float sigm_f(float x){ return 1.0f / (1.0f + expf(-x)); }

// ---------------- edge geometry: y1(3), Ay(9), rbf(8) -> egeo stride 20; + dst histogram ----
__global__ void geom_kernel(const float* __restrict__ pos, const int* __restrict__ ei,
                            float* __restrict__ egeo, int* __restrict__ cnt) {
  int e = blockIdx.x * 256 + threadIdx.x;
  if (e >= NE) return;
  int s = ei[e], d = ei[NE + e];
  atomicAdd(&cnt[d], 1);
  float rx = pos[d*3+0] - pos[s*3+0];
  float ry = pos[d*3+1] - pos[s*3+1];
  float rz = pos[d*3+2] - pos[s*3+2];
  float r = sqrtf(rx*rx + ry*ry + rz*rz);
  r = fmaxf(r, 1e-6f);
  float x = rx / r, y = ry / r, z = rz / r;
  const float s3 = 1.7320508075688772f;
  const float c15 = 3.872983346207417f;
  float y2_0 = c15 * x * y;
  float y2_1 = c15 * y * z;
  float y2_2 = 1.118033988749895f * (3.0f*z*z - 1.0f);
  float y2_3 = c15 * x * z;
  float y2_4 = 1.9364916731037085f * (x*x - y*y);
  const float q2 = 0.7071067811865476f;
  const float q6 = 0.4082482904638631f;
  float* g = egeo + (size_t)e * 20;
  g[0] = s3 * x; g[1] = s3 * y; g[2] = s3 * z;
  g[3+0] = -q6*y2_2 + q2*y2_4;
  g[3+1] =  q2*y2_0;
  g[3+2] =  q2*y2_3;
  g[3+3] =  q2*y2_0;
  g[3+4] = -q6*y2_2 - q2*y2_4;
  g[3+5] =  q2*y2_1;
  g[3+6] =  q2*y2_3;
  g[3+7] =  q2*y2_1;
  g[3+8] =  2.0f*q6*y2_2;
  float u = r / 6.0f;
  float fc = 0.0f;
  if (u < 1.0f) {
    float u2=u*u, u3=u2*u, u6=u3*u3, u7=u6*u, u8=u7*u;
    fc = 1.0f - 28.0f*u6 + 48.0f*u7 - 21.0f*u8;
  }
  const float pref = 0.5773502691896258f;
  const float pi6 = 0.5235987755982988f;
  #pragma unroll
  for (int n = 1; n <= 8; n++) {
    g[12 + n - 1] = pref * sinf((float)n * pi6 * r) / r * fc;
  }
}

// ---------------- CSR scan ----------------
__global__ void scan_kernel(const int* __restrict__ cnt, int* __restrict__ offs,
                            int* __restrict__ cursor) {
  __shared__ int part[256];
  int t = threadIdx.x;
  int local[8];
  int s = 0;
  #pragma unroll
  for (int j = 0; j < 8; j++) { local[j] = s; s += cnt[t*8 + j]; }
  part[t] = s;
  __syncthreads();
  for (int off = 1; off < 256; off <<= 1) {
    int v = part[t];
    int add = (t >= off) ? part[t - off] : 0;
    __syncthreads();
    part[t] = v + add;
    __syncthreads();
  }
  int excl = (t == 0) ? 0 : part[t-1];
  #pragma unroll
  for (int j = 0; j < 8; j++) {
    int o = excl + local[j];
    offs[t*8 + j] = o;
    cursor[t*8 + j] = o;
  }
  if (t == 255) offs[2048] = part[255];
}

// scatter: record each edge's CSR slot (epos) so edge_msg can write msg in CSR order
__global__ void scatter_kernel(const int* __restrict__ ei, int* __restrict__ cursor,
                               int* __restrict__ epos) {
  int e = blockIdx.x * 256 + threadIdx.x;
  if (e >= NE) return;
  int d = ei[NE + e];
  int p = atomicAdd(&cursor[d], 1);
  epos[e] = p;
}

// ---------------- W3 -> f16, MFMA-B-fragment-ordered ----------------
__global__ void conv_w3_kernel(const float* __restrict__ w3g, _Float16* __restrict__ w3h) {
  int tid = blockIdx.x * 256 + threadIdx.x;
  if (tid >= 16 * WNUM) return;
  int n = tid % WNUM;
  int lq = tid / WNUM;           // l*4 + quad
  int quad = lq & 3, l = lq >> 2;
  const float* src = w3g + (size_t)l * 64 * WNUM + n;
  int idx = n >> 4, L = n & 15;
  _Float16* dst = w3h + ((size_t)(l * 208 + idx) * 2) * 512 + (quad*16 + L) * 8;
  half8 h0, h1;
  #pragma unroll
  for (int j = 0; j < 8; j++) {
    h0[j] = (_Float16)src[(size_t)(quad*8 + j) * WNUM];
    h1[j] = (_Float16)src[(size_t)(32 + quad*8 + j) * WNUM];
  }
  *(half8*)(dst)       = h0;
  *(half8*)(dst + 512) = h1;
}

// ---------------- W2 -> f16, MFMA-B-fragment-ordered (for radial MFMA) ----------------
__global__ void conv_w2_kernel(const float* __restrict__ w2g, _Float16* __restrict__ w2h) {
  int tid = blockIdx.x * 256 + threadIdx.x;
  if (tid >= 16384) return;
  int j = tid & 7, lane = (tid >> 3) & 63, plane = (tid >> 9) & 1;
  int ct = (tid >> 10) & 3, l = tid >> 12;
  int q = lane >> 4, Lc = lane & 15;
  int k = plane*32 + q*8 + j;
  int n = ct*16 + Lc;
  w2h[tid] = (_Float16)w2g[(size_t)l*4096 + k*64 + n];
}

// ---------------- radial MLP via MFMA: f = silu(silu(rbf@W1+b1)@W2+b2) -> f16 ----
__global__ void radial_mfma_kernel(const float* __restrict__ egeo,
                                   const float* __restrict__ w1, const float* __restrict__ b1,
                                   const float* __restrict__ b2,
                                   const _Float16* __restrict__ w2h,
                                   _Float16* __restrict__ f_h) {
  __shared__ _Float16 h1s[64*72];
  const int t = threadIdx.x;
  const int l = blockIdx.x / (NE/64);
  const int e0 = (blockIdx.x % (NE/64)) * 64;
  const float* w1l = w1 + (size_t)l * 512;
  _Float16* fl = f_h + (size_t)l * NE * 64;

  {
    int e = t >> 2, jb = (t & 3) * 16;
    const float* rb = egeo + (size_t)(e0 + e) * 20 + 12;
    float r0 = rb[0], r1 = rb[1], r2 = rb[2], r3 = rb[3];
    float r4 = rb[4], r5 = rb[5], r6 = rb[6], r7 = rb[7];
    #pragma unroll
    for (int jj = 0; jj < 16; ++jj) {
      int j = jb + jj;
      float acc = b1[l*64 + j];
      acc += r0 * w1l[0*64 + j];
      acc += r1 * w1l[1*64 + j];
      acc += r2 * w1l[2*64 + j];
      acc += r3 * w1l[3*64 + j];
      acc += r4 * w1l[4*64 + j];
      acc += r5 * w1l[5*64 + j];
      acc += r6 * w1l[6*64 + j];
      acc += r7 * w1l[7*64 + j];
      h1s[e*72 + j] = (_Float16)silu_f(acc);
    }
  }
  __syncthreads();

  const int wv = t >> 6, lane = t & 63, L = lane & 15, quad = lane >> 4;
  half8 A0 = *(const half8*)&h1s[(wv*16 + L)*72 + quad*8];
  half8 A1 = *(const half8*)&h1s[(wv*16 + L)*72 + 32 + quad*8];
  #pragma unroll
  for (int ct = 0; ct < 4; ++ct) {
    const _Float16* wB = w2h + ((size_t)(l*4 + ct) * 2) * 512 + lane*8;
    half8 B0 = *(const half8*)(wB);
    half8 B1 = *(const half8*)(wB + 512);
    float bb = b2[l*64 + ct*16 + L];
    f32x4 acc = {bb, bb, bb, bb};
    acc = __builtin_amdgcn_mfma_f32_16x16x32_f16(A0, B0, acc, 0, 0, 0);
    acc = __builtin_amdgcn_mfma_f32_16x16x32_f16(A1, B1, acc, 0, 0, 0);
    #pragma unroll
    for (int r = 0; r < 4; ++r) {
      fl[(size_t)(e0 + wv*16 + quad*4 + r)*64 + ct*16 + L] = (_Float16)silu_f(acc[r]);
    }
  }
}

// ---------------- embed + layer-0 node linears (h v-part = 0 => hx/xself v-part = 0) ---
__global__ void embed_prep_kernel(const float* __restrict__ x, const float* __restrict__ ew,
                                  const float* __restrict__ lws0, const float* __restrict__ sws0,
                                  float* __restrict__ h, float* __restrict__ hx,
                                  float* __restrict__ xself) {
  __shared__ float hs[8][32];
  int t = threadIdx.x;
  int nl = t >> 5, c = t & 31;
  int n = blockIdx.x * 8 + nl;
  float v = 0.0f;
  #pragma unroll
  for (int j = 0; j < 16; j++) v += x[n*16 + j] * ew[j*32 + c];
  v *= 0.25f;
  hs[nl][c] = v;
  h[(size_t)n*80 + c] = v;
  for (int idx = t; idx < 8*48; idx += 256) {
    int nn = blockIdx.x * 8 + idx / 48;
    h[(size_t)nn*80 + 32 + idx % 48] = 0.0f;
  }
  __syncthreads();
  for (int idx = t; idx < 2*8*80; idx += 256) {
    int which = idx / 640, r = idx % 640;
    int nl2 = r / 80, cc = r % 80;
    int n2 = blockIdx.x * 8 + nl2;
    float o = 0.0f;
    if (cc < 32) {
      const float* W = which ? sws0 : lws0;
      #pragma unroll 8
      for (int u = 0; u < 32; u++) o += hs[nl2][u] * W[u*32 + cc];
      o *= 0.17677669529663687f;
    }
    (which ? xself : hx)[(size_t)n2*80 + cc] = o;
  }
}

// ---------------- fused MFMA weight-GEMM (f16) + tensor product -> msg (CSR order) ----
// R16-EXACT K-loop — FROZEN (R15/R17: any restructuring spills at the 128-VGPR cap).
// Only change vs R19: msg stored as f16 (epilogue-only conversion, outside the
// register-critical loops). WRITE_SIZE halves; agg gather traffic halves.
__launch_bounds__(256, 2)
__global__ void edge_msg_kernel(const int* __restrict__ ei, const float* __restrict__ egeo,
                                const _Float16* __restrict__ f_h,
                                const float* __restrict__ hx,
                                const _Float16* __restrict__ w3h,
                                const float* __restrict__ b3g,
                                const int* __restrict__ epos,
                                _Float16* __restrict__ msg, int l) {
  __shared__ float smem[15616];            // 62.5 KB
  __shared__ int eposS[64];
  float* sT    = smem;                     // [32][64]
  float* p2T   = smem + 2048;              // [16][64]
  float* q3T   = smem + 3072;              // [48][64]  s_u * y1_i
  float* vT    = smem + 6144;              // [48][64]
  float* q5T   = smem + 9216;              // [48][64]
  float* biasL = smem + 12288;             // [3328]
  float* poolA = smem;                     // post-loop overlay (sT+p2T dead)
  float* poolB = smem + 3072;              // overlay (q3T dead)
  float* poolC = smem + 6144;              // overlay (vT dead)

  const int t = threadIdx.x;
  const int e0 = blockIdx.x * 64;
  const float* b3l = b3g + (size_t)l * WNUM;

  // ---- prologue ----
  for (int i = t; i < WNUM; i += 256) biasL[i] = b3l[i];
  if (t < 64) eposS[t] = epos[e0 + t];
  for (int idx = t; idx < 64*80; idx += 256) {
    int e = idx / 80, c = idx % 80;
    int src = ei[e0 + e];
    float val = hx[(size_t)src*80 + c];
    if (c < 32) sT[c*64 + e] = val; else vT[(c-32)*64 + e] = val;
  }
  __syncthreads();
  for (int idx = t; idx < 64*16; idx += 256) {
    int u = idx >> 6, e = idx & 63;
    const float* g = &egeo[(size_t)(e0+e)*20];
    float a = vT[(u*3)*64+e]*g[0] + vT[(u*3+1)*64+e]*g[1] + vT[(u*3+2)*64+e]*g[2];
    p2T[u*64 + e] = a * 0.5773502691896258f;
  }
  for (int idx = t; idx < 64*48; idx += 256) {
    int o = idx >> 6, e = idx & 63;
    int u = o / 3, jj = o % 3;
    const float* g = &egeo[(size_t)(e0+e)*20];
    q3T[o*64 + e] = sT[u*64 + e] * g[jj];
    float a = vT[(u*3)*64+e]*g[3+jj] + vT[(u*3+1)*64+e]*g[6+jj] + vT[(u*3+2)*64+e]*g[9+jj];
    q5T[o*64 + e] = a * 0.7745966692414834f;
  }

  const int wv = t >> 6, lane = t & 63, L = lane & 15, quad = lane >> 4;
  const int qb = quad * 4;

  // A fragments for all 4 edge-groups (32 VGPR)
  half8 Ah[4][2];
  #pragma unroll
  for (int g = 0; g < 4; ++g) {
    const half8* fA = (const half8*)(f_h + (size_t)(e0 + g*16 + L)*64);
    Ah[g][0] = fA[quad];
    Ah[g][1] = fA[4 + quad];
  }
  __syncthreads();   // LDS (factors + bias + epos) ready

  const _Float16* wb = w3h + (size_t)l * 208 * 1024 + lane * 8;
  half8 pb0[4], pb1[4];
  float bs[4];

#define PRIME(START)                                                          \
  { _Pragma("unroll")                                                         \
    for (int _s = 0; _s < 4; ++_s) {                                          \
      const _Float16* _wn = wb + (size_t)((START) + _s) * 1024;               \
      pb0[_s] = *(const half8*)_wn;                                           \
      pb1[_s] = *(const half8*)(_wn + 512);                                   \
      bs[_s] = biasL[((START) + _s)*16 + L];                                  \
    } }

  // declares a0..a3 (one per edge-group); CO compile-time
#define GCORE(IDX, CO, OKCOND)                                                \
  f32x4 a0, a1, a2, a3;                                                       \
  { half8 _B0 = pb0[(CO)&3], _B1 = pb1[(CO)&3];                               \
    float _bb = bs[(CO)&3];                                                   \
    if (OKCOND) {                                                             \
      const _Float16* _wn = wb + (size_t)((IDX) + 4) * 1024;                  \
      pb0[(CO)&3] = *(const half8*)_wn;                                       \
      pb1[(CO)&3] = *(const half8*)(_wn + 512);                               \
      bs[(CO)&3] = biasL[((IDX) + 4)*16 + L];                                 \
    }                                                                         \
    a0 = (f32x4){_bb,_bb,_bb,_bb}; a1 = a0; a2 = a0; a3 = a0;                 \
    a0 = __builtin_amdgcn_mfma_f32_16x16x32_f16(Ah[0][0], _B0, a0, 0,0,0);    \
    a0 = __builtin_amdgcn_mfma_f32_16x16x32_f16(Ah[0][1], _B1, a0, 0,0,0);    \
    a1 = __builtin_amdgcn_mfma_f32_16x16x32_f16(Ah[1][0], _B0, a1, 0,0,0);    \
    a1 = __builtin_amdgcn_mfma_f32_16x16x32_f16(Ah[1][1], _B1, a1, 0,0,0);    \
    a2 = __builtin_amdgcn_mfma_f32_16x16x32_f16(Ah[2][0], _B0, a2, 0,0,0);    \
    a2 = __builtin_amdgcn_mfma_f32_16x16x32_f16(Ah[2][1], _B1, a2, 0,0,0);    \
    a3 = __builtin_amdgcn_mfma_f32_16x16x32_f16(Ah[3][0], _B0, a3, 0,0,0);    \
    a3 = __builtin_amdgcn_mfma_f32_16x16x32_f16(Ah[3][1], _B1, a3, 0,0,0);    \
  }

  const float S48 = 0.14433756729740645f;  // 1/sqrt(48)
  const float S64 = 0.125f;                // 1/sqrt(64)

  if (wv <= 1) {
    f32x4 ms[4][3];
    #pragma unroll
    for (int g = 0; g < 4; ++g)
      #pragma unroll
      for (int j = 0; j < 3; ++j) ms[g][j] = (f32x4){0,0,0,0};
    const int ustart = wv * 16, istart = wv * 48, iend = istart + 48;
    PRIME(istart);
    for (int u4 = 0; u4 < 16; u4 += 4) {
      #pragma unroll
      for (int uu = 0; uu < 4; ++uu) {
        const int u = u4 + uu;
        f32x4 f0 = *(const f32x4*)&sT[(ustart+u)*64 + qb];
        f32x4 f1 = *(const f32x4*)&sT[(ustart+u)*64 + 16 + qb];
        f32x4 f2 = *(const f32x4*)&sT[(ustart+u)*64 + 32 + qb];
        f32x4 f3 = *(const f32x4*)&sT[(ustart+u)*64 + 48 + qb];
        #pragma unroll
        for (int j = 0; j < 3; ++j) {
          const int CO = uu*3 + j;
          const int idx = istart + u4*3 + CO;
          GCORE(idx, CO, idx + 4 < iend);
          ms[0][j] += f0*a0; ms[1][j] += f1*a1; ms[2][j] += f2*a2; ms[3][j] += f3*a3;
        }
      }
    }
    float* pool = (wv == 0) ? poolA : poolB;
    __syncthreads();
    #pragma unroll
    for (int g = 0; g < 4; ++g)
      #pragma unroll
      for (int j = 0; j < 3; ++j)
        #pragma unroll
        for (int r = 0; r < 4; ++r)
          pool[(g*16 + qb + r)*48 + j*16 + L] = ms[g][j][r];
    __syncthreads();
  } else if (wv == 2) {
    f32x4 ms[4][3], mv[4][3];
    #pragma unroll
    for (int g = 0; g < 4; ++g)
      #pragma unroll
      for (int j = 0; j < 3; ++j) { ms[g][j] = (f32x4){0,0,0,0}; mv[g][j] = (f32x4){0,0,0,0}; }
    PRIME(96);
    for (int u4 = 0; u4 < 16; u4 += 4) {
      #pragma unroll
      for (int uu = 0; uu < 4; ++uu) {
        const int u = u4 + uu;
        f32x4 f0 = *(const f32x4*)&p2T[u*64 + qb];
        f32x4 f1 = *(const f32x4*)&p2T[u*64 + 16 + qb];
        f32x4 f2 = *(const f32x4*)&p2T[u*64 + 32 + qb];
        f32x4 f3 = *(const f32x4*)&p2T[u*64 + 48 + qb];
        #pragma unroll
        for (int j = 0; j < 3; ++j) {
          const int CO = uu*3 + j;
          const int idx = 96 + u4*3 + CO;
          GCORE(idx, CO, idx + 4 < 144);
          ms[0][j] += f0*a0; ms[1][j] += f1*a1; ms[2][j] += f2*a2; ms[3][j] += f3*a3;
        }
      }
    }
    PRIME(176);
    for (int u4 = 0; u4 < 16; u4 += 4) {
      #pragma unroll
      for (int uu = 0; uu < 4; ++uu) {
        const int u = u4 + uu;
        const int idx = 176 + u;
        GCORE(idx, uu, idx + 4 < 192);
        #pragma unroll
        for (int i = 0; i < 3; ++i) {
          mv[0][i] += *(const f32x4*)&vT[(u*3+i)*64 + qb]      * a0;
          mv[1][i] += *(const f32x4*)&vT[(u*3+i)*64 + 16 + qb] * a1;
          mv[2][i] += *(const f32x4*)&vT[(u*3+i)*64 + 32 + qb] * a2;
          mv[3][i] += *(const f32x4*)&vT[(u*3+i)*64 + 48 + qb] * a3;
        }
      }
    }
    __syncthreads();
    #pragma unroll
    for (int g = 0; g < 4; ++g)
      #pragma unroll
      for (int i = 0; i < 3; ++i)
        #pragma unroll
        for (int r = 0; r < 4; ++r)
          poolC[(g*16 + qb + r)*48 + i*16 + L] = mv[g][i][r];
    __syncthreads();
    #pragma unroll
    for (int g = 0; g < 4; ++g) {
      #pragma unroll
      for (int r = 0; r < 4; ++r) {
        const int eb = g*16 + qb + r;
        _Float16* mp = msg + (size_t)eposS[eb]*96;
        #pragma unroll
        for (int j = 0; j < 3; ++j)
          mp[j*16 + L] = (_Float16)((ms[g][j][r] + poolA[eb*48 + j*16 + L] + poolB[eb*48 + j*16 + L]) * S48);
      }
    }
  } else {
    f32x4 mv[4][3];
    #pragma unroll
    for (int g = 0; g < 4; ++g)
      #pragma unroll
      for (int i = 0; i < 3; ++i) mv[g][i] = (f32x4){0,0,0,0};
    PRIME(144);
    for (int u4 = 0; u4 < 32; u4 += 4) {
      #pragma unroll
      for (int uu = 0; uu < 4; ++uu) {
        const int u = u4 + uu;
        const int idx = 144 + u;
        GCORE(idx, uu, idx + 4 < 176);
        #pragma unroll
        for (int i = 0; i < 3; ++i) {
          mv[0][i] += *(const f32x4*)&q3T[(u*3+i)*64 + qb]      * a0;
          mv[1][i] += *(const f32x4*)&q3T[(u*3+i)*64 + 16 + qb] * a1;
          mv[2][i] += *(const f32x4*)&q3T[(u*3+i)*64 + 32 + qb] * a2;
          mv[3][i] += *(const f32x4*)&q3T[(u*3+i)*64 + 48 + qb] * a3;
        }
      }
    }
    PRIME(192);
    for (int u4 = 0; u4 < 16; u4 += 4) {
      #pragma unroll
      for (int uu = 0; uu < 4; ++uu) {
        const int u = u4 + uu;
        const int idx = 192 + u;
        GCORE(idx, uu, idx + 4 < 208);
        #pragma unroll
        for (int i = 0; i < 3; ++i) {
          mv[0][i] += *(const f32x4*)&q5T[(u*3+i)*64 + qb]      * a0;
          mv[1][i] += *(const f32x4*)&q5T[(u*3+i)*64 + 16 + qb] * a1;
          mv[2][i] += *(const f32x4*)&q5T[(u*3+i)*64 + 32 + qb] * a2;
          mv[3][i] += *(const f32x4*)&q5T[(u*3+i)*64 + 48 + qb] * a3;
        }
      }
    }
    __syncthreads();
    __syncthreads();
    #pragma unroll
    for (int g = 0; g < 4; ++g) {
      #pragma unroll
      for (int r = 0; r < 4; ++r) {
        const int eb = g*16 + qb + r;
        _Float16* mp = msg + (size_t)eposS[eb]*96;
        #pragma unroll
        for (int i = 0; i < 3; ++i)
          mp[48 + 3*L + i] = (_Float16)((mv[g][i][r] + poolC[eb*48 + i*16 + L]) * S64);
      }
    }
  }
#undef GCORE
#undef PRIME
}

// ---------------- fused: CSR-streaming gather (f16 msg) + node update + next linears ----
__global__ void agg_fused_kernel(const _Float16* __restrict__ msg, const int* __restrict__ offs,
                                 const float* __restrict__ xself_in, float* __restrict__ h,
                                 const float* __restrict__ lwsN, const float* __restrict__ lwvN,
                                 const float* __restrict__ swsN, const float* __restrict__ swvN,
                                 float* __restrict__ hx_out, float* __restrict__ xself_out,
                                 const float* __restrict__ pw, float* __restrict__ out,
                                 int last) {
  __shared__ float sagg[4][96];
  __shared__ float hnew[4][80];
  int t = threadIdx.x;
  int nb = blockIdx.x * 4;
  for (int idx = t; idx < 4*96; idx += 256) {
    int nl = idx / 96, c = idx % 96;
    int n = nb + nl;
    int b = offs[n], e = offs[n+1];
    float acc = 0.0f, acc2 = 0.0f;
    int j = b;
    for (; j + 1 < e; j += 2) {
      acc  += (float)msg[(size_t)j*96 + c];
      acc2 += (float)msg[(size_t)(j+1)*96 + c];
    }
    if (j < e) acc += (float)msg[(size_t)j*96 + c];
    sagg[nl][c] = (acc + acc2) * 0.20412414523193154f;   // 1/sqrt(24)
  }
  __syncthreads();
  for (int idx = t; idx < 4*80; idx += 256) {
    int nl = idx / 80, c = idx % 80;
    int n = nb + nl;
    float a;
    if (c < 32) {
      a = silu_f(sagg[nl][c]);
    } else {
      int oc = c - 32, wch = oc / 3;
      a = sagg[nl][48 + oc] * sigm_f(sagg[nl][32 + wch]);
    }
    float hn = h[(size_t)n*80 + c] + xself_in[(size_t)n*80 + c] + a;
    hnew[nl][c] = hn;
    h[(size_t)n*80 + c] = hn;
  }
  __syncthreads();
  if (!last) {
    for (int idx = t; idx < 2*4*80; idx += 256) {
      int which = idx / 320, r = idx % 320;
      int nl = r / 80, c = r % 80;
      int n = nb + nl;
      const float* Ws = which ? swsN : lwsN;
      const float* Wv = which ? swvN : lwvN;
      float v = 0.0f;
      if (c < 32) {
        #pragma unroll 8
        for (int u = 0; u < 32; u++) v += hnew[nl][u] * Ws[u*32 + c];
        v *= 0.17677669529663687f;
      } else {
        int oc = c - 32, wch = oc / 3, i = oc % 3;
        #pragma unroll
        for (int u = 0; u < 16; u++) v += hnew[nl][32 + u*3 + i] * Wv[u*16 + wch];
        v *= 0.25f;
      }
      (which ? xself_out : hx_out)[(size_t)n*80 + c] = v;
    }
  } else {
    for (int idx = t; idx < 4*32; idx += 256) {
      int nl = idx / 32, c = idx % 32;
      int n = nb + nl;
      float acc = 0.0f;
      #pragma unroll 8
      for (int u = 0; u < 32; u++) acc += hnew[nl][u] * pw[u*32 + c];
      out[(size_t)n*32 + c] = acc * 0.17677669529663687f;
    }
  }
}

extern "C" void kernel_launch(void* const* d_in, const int* in_sizes, int n_in,
                              void* d_out, int out_size, void* d_ws, size_t ws_size,
                              hipStream_t stream) {
  const float* x       = (const float*)d_in[0];
  const float* pos     = (const float*)d_in[1];
  const int*   ei      = (const int*)  d_in[2];
  const float* embed_w = (const float*)d_in[3];
  const float* proj_w  = (const float*)d_in[4];
  const float* lin_ws  = (const float*)d_in[5];
  const float* lin_wv  = (const float*)d_in[6];
  const float* sc_ws   = (const float*)d_in[7];
  const float* sc_wv   = (const float*)d_in[8];
  const float* mlp_w1  = (const float*)d_in[9];
  const float* mlp_b1  = (const float*)d_in[10];
  const float* mlp_w2  = (const float*)d_in[11];
  const float* mlp_b2  = (const float*)d_in[12];
  const float* mlp_w3  = (const float*)d_in[13];
  const float* mlp_b3  = (const float*)d_in[14];
  float* out = (float*)d_out;

  float* ws    = (float*)d_ws;
  float* egeo  = ws;                          // NE*20
  float* h     = egeo  + (size_t)NE*20;       // NN*80
  float* hx    = h     + (size_t)NN*80;       // NN*80
  float* xself = hx    + (size_t)NN*80;       // NN*80
  _Float16* msg = (_Float16*)(xself + (size_t)NN*80); // NE*96 f16 (CSR-ordered rows)
  _Float16* f_h = msg + (size_t)NE*96;                // 4*NE*64 f16 (all layers)
  _Float16* w3h = f_h + (size_t)4*NE*64;              // 4*208*1024 f16
  _Float16* w2h = w3h + (size_t)4*208*1024;           // 16384 f16 (32 KB)
  int* cnt    = (int*)(w2h + 16384);          // NN
  int* offs   = cnt + NN;                     // NN+1
  int* cursor = offs + NN + 1;                // NN
  int* epos   = cursor + NN;                  // NE

  hipMemsetAsync(cnt, 0, NN*sizeof(int), stream);
  geom_kernel<<<(NE + 255)/256, 256, 0, stream>>>(pos, ei, egeo, cnt);
  scan_kernel<<<1, 256, 0, stream>>>(cnt, offs, cursor);
  scatter_kernel<<<NE/256, 256, 0, stream>>>(ei, cursor, epos);
  conv_w3_kernel<<<(16*WNUM + 255)/256, 256, 0, stream>>>(mlp_w3, w3h);
  conv_w2_kernel<<<64, 256, 0, stream>>>(mlp_w2, w2h);
  radial_mfma_kernel<<<4*(NE/64), 256, 0, stream>>>(egeo, mlp_w1, mlp_b1, mlp_b2, w2h, f_h);
  embed_prep_kernel<<<NN/8, 256, 0, stream>>>(x, embed_w, lin_ws, sc_ws, h, hx, xself);

  for (int l = 0; l < 4; l++) {
    edge_msg_kernel<<<NE/64, 256, 0, stream>>>(ei, egeo, f_h + (size_t)l*NE*64, hx,
                                               w3h, mlp_b3, epos, msg, l);
    int last = (l == 3);
    agg_fused_kernel<<<NN/4, 256, 0, stream>>>(
        msg, offs, xself, h,
        lin_ws + (size_t)(l+1 < 4 ? l+1 : 0) * 1024,
        lin_wv + (size_t)(l+1 < 4 ? l+1 : 0) * 256,
        sc_ws  + (size_t)(l+1 < 4 ? l+1 : 0) * 1024,
        sc_wv  + (size_t)(l+1 < 4 ? l+1 : 0) * 256,
        hx, xself, proj_w, out, last);
  }
}

// Round 22
// 429.885 us; speedup vs baseline: 1.5454x; 1.0319x over previous
//
#include <hip/hip_runtime.h>
#include <math.h>

#define NN 2048
#define NE 49152
#define WNUM 3328

typedef __attribute__((ext_vector_type(8))) _Float16 half8;
typedef __attribute__((ext_vector_type(4))) float f32x4;

__device__ __forceinline__ float silu_f(float x){ return x / (1.0f + expf(-x)); }
__device__ __forceinline__ float sigm_f(float x){ return 1.0f / (1.0f + expf(-x)); }

// ---------------- edge geometry: y1(3), Ay(9), rbf(8) -> egeo stride 20; + dst histogram ----
__global__ void geom_kernel(const float* __restrict__ pos, const int* __restrict__ ei,
                            float* __restrict__ egeo, int* __restrict__ cnt) {
  int e = blockIdx.x * 256 + threadIdx.x;
  if (e >= NE) return;
  int s = ei[e], d = ei[NE + e];
  atomicAdd(&cnt[d], 1);
  float rx = pos[d*3+0] - pos[s*3+0];
  float ry = pos[d*3+1] - pos[s*3+1];
  float rz = pos[d*3+2] - pos[s*3+2];
  float r = sqrtf(rx*rx + ry*ry + rz*rz);
  r = fmaxf(r, 1e-6f);
  float x = rx / r, y = ry / r, z = rz / r;
  const float s3 = 1.7320508075688772f;
  const float c15 = 3.872983346207417f;
  float y2_0 = c15 * x * y;
  float y2_1 = c15 * y * z;
  float y2_2 = 1.118033988749895f * (3.0f*z*z - 1.0f);
  float y2_3 = c15 * x * z;
  float y2_4 = 1.9364916731037085f * (x*x - y*y);
  const float q2 = 0.7071067811865476f;
  const float q6 = 0.4082482904638631f;
  float* g = egeo + (size_t)e * 20;
  g[0] = s3 * x; g[1] = s3 * y; g[2] = s3 * z;
  g[3+0] = -q6*y2_2 + q2*y2_4;
  g[3+1] =  q2*y2_0;
  g[3+2] =  q2*y2_3;
  g[3+3] =  q2*y2_0;
  g[3+4] = -q6*y2_2 - q2*y2_4;
  g[3+5] =  q2*y2_1;
  g[3+6] =  q2*y2_3;
  g[3+7] =  q2*y2_1;
  g[3+8] =  2.0f*q6*y2_2;
  float u = r / 6.0f;
  float fc = 0.0f;
  if (u < 1.0f) {
    float u2=u*u, u3=u2*u, u6=u3*u3, u7=u6*u, u8=u7*u;
    fc = 1.0f - 28.0f*u6 + 48.0f*u7 - 21.0f*u8;
  }
  const float pref = 0.5773502691896258f;
  const float pi6 = 0.5235987755982988f;
  #pragma unroll
  for (int n = 1; n <= 8; n++) {
    g[12 + n - 1] = pref * sinf((float)n * pi6 * r) / r * fc;
  }
}

// ---------------- CSR scan ----------------
__global__ void scan_kernel(const int* __restrict__ cnt, int* __restrict__ offs,
                            int* __restrict__ cursor) {
  __shared__ int part[256];
  int t = threadIdx.x;
  int local[8];
  int s = 0;
  #pragma unroll
  for (int j = 0; j < 8; j++) { local[j] = s; s += cnt[t*8 + j]; }
  part[t] = s;
  __syncthreads();
  for (int off = 1; off < 256; off <<= 1) {
    int v = part[t];
    int add = (t >= off) ? part[t - off] : 0;
    __syncthreads();
    part[t] = v + add;
    __syncthreads();
  }
  int excl = (t == 0) ? 0 : part[t-1];
  #pragma unroll
  for (int j = 0; j < 8; j++) {
    int o = excl + local[j];
    offs[t*8 + j] = o;
    cursor[t*8 + j] = o;
  }
  if (t == 255) offs[2048] = part[255];
}

// ---------------- W2 -> f16, MFMA-B-fragment-ordered — SEPARATE launch (must complete
// before prologue_fused's radial sub-blocks read w2h; same-launch = race, R21 bug) ----
__global__ void conv_w2_kernel(const float* __restrict__ w2g, _Float16* __restrict__ w2h) {
  int tid = blockIdx.x * 256 + threadIdx.x;
  if (tid >= 16384) return;
  int j = tid & 7, lane = (tid >> 3) & 63, plane = (tid >> 9) & 1;
  int ct = (tid >> 10) & 3, l = tid >> 12;
  int q = lane >> 4, Lc = lane & 15;
  int k = plane*32 + q*8 + j;
  int n = ct*16 + Lc;
  w2h[tid] = (_Float16)w2g[(size_t)l*4096 + k*64 + n];
}

// ---------------- fused prologue: scatter | conv_w3 | radial_mfma | embed ----
// All sub-kernels depend only on geom/scan/conv_w2 output (all earlier launches)
// and are mutually independent — no intra-launch producer-consumer pairs.
#define PB_SCAT  192                 // scatter: NE/256
#define PB_W3    208                 // conv_w3: (16*WNUM+255)/256
#define PB_RAD   3072                // radial: 4*(NE/64)
#define PB_EMB   256                 // embed_prep: NN/8
__global__ void prologue_fused_kernel(
    const int* __restrict__ ei, int* __restrict__ cursor, int* __restrict__ epos,
    const float* __restrict__ w3g, _Float16* __restrict__ w3h,
    const _Float16* __restrict__ w2h,
    const float* __restrict__ egeo,
    const float* __restrict__ w1, const float* __restrict__ b1,
    const float* __restrict__ b2, _Float16* __restrict__ f_h,
    const float* __restrict__ x, const float* __restrict__ ew,
    const float* __restrict__ lws0, const float* __restrict__ sws0,
    float* __restrict__ h, _Float16* __restrict__ hx, float* __restrict__ xself) {
  __shared__ float smem[2304];   // radial h1s (64*72 f16) / embed hs
  const int blk = blockIdx.x;
  const int t = threadIdx.x;

  if (blk < PB_SCAT) {
    // ---- scatter ----
    int e = blk * 256 + t;
    int d = ei[NE + e];
    int p = atomicAdd(&cursor[d], 1);
    epos[e] = p;
  } else if (blk < PB_SCAT + PB_W3) {
    // ---- conv_w3 ----
    int tid = (blk - PB_SCAT) * 256 + t;
    if (tid >= 16 * WNUM) return;
    int n = tid % WNUM;
    int lq = tid / WNUM;
    int quad = lq & 3, l = lq >> 2;
    const float* src = w3g + (size_t)l * 64 * WNUM + n;
    int idx = n >> 4, L = n & 15;
    _Float16* dst = w3h + ((size_t)(l * 208 + idx) * 2) * 512 + (quad*16 + L) * 8;
    half8 h0, h1;
    #pragma unroll
    for (int j = 0; j < 8; j++) {
      h0[j] = (_Float16)src[(size_t)(quad*8 + j) * WNUM];
      h1[j] = (_Float16)src[(size_t)(32 + quad*8 + j) * WNUM];
    }
    *(half8*)(dst)       = h0;
    *(half8*)(dst + 512) = h1;
  } else if (blk < PB_SCAT + PB_W3 + PB_RAD) {
    // ---- radial MFMA (reads w2h from the PREVIOUS launch — safe) ----
    _Float16* h1s = (_Float16*)smem;   // 64*72 f16
    int rb = blk - PB_SCAT - PB_W3;
    const int l = rb / (NE/64);
    const int e0 = (rb % (NE/64)) * 64;
    const float* w1l = w1 + (size_t)l * 512;
    _Float16* fl = f_h + (size_t)l * NE * 64;
    {
      int e = t >> 2, jb = (t & 3) * 16;
      const float* rbp = egeo + (size_t)(e0 + e) * 20 + 12;
      float r0 = rbp[0], r1 = rbp[1], r2 = rbp[2], r3 = rbp[3];
      float r4 = rbp[4], r5 = rbp[5], r6 = rbp[6], r7 = rbp[7];
      #pragma unroll
      for (int jj = 0; jj < 16; ++jj) {
        int j = jb + jj;
        float acc = b1[l*64 + j];
        acc += r0 * w1l[0*64 + j];
        acc += r1 * w1l[1*64 + j];
        acc += r2 * w1l[2*64 + j];
        acc += r3 * w1l[3*64 + j];
        acc += r4 * w1l[4*64 + j];
        acc += r5 * w1l[5*64 + j];
        acc += r6 * w1l[6*64 + j];
        acc += r7 * w1l[7*64 + j];
        h1s[e*72 + j] = (_Float16)silu_f(acc);
      }
    }
    __syncthreads();
    const int wv = t >> 6, lane = t & 63, L = lane & 15, quad = lane >> 4;
    half8 A0 = *(const half8*)&h1s[(wv*16 + L)*72 + quad*8];
    half8 A1 = *(const half8*)&h1s[(wv*16 + L)*72 + 32 + quad*8];
    #pragma unroll
    for (int ct = 0; ct < 4; ++ct) {
      const _Float16* wB = w2h + ((size_t)(l*4 + ct) * 2) * 512 + lane*8;
      half8 B0 = *(const half8*)(wB);
      half8 B1 = *(const half8*)(wB + 512);
      float bb = b2[l*64 + ct*16 + L];
      f32x4 acc = {bb, bb, bb, bb};
      acc = __builtin_amdgcn_mfma_f32_16x16x32_f16(A0, B0, acc, 0, 0, 0);
      acc = __builtin_amdgcn_mfma_f32_16x16x32_f16(A1, B1, acc, 0, 0, 0);
      #pragma unroll
      for (int r = 0; r < 4; ++r) {
        fl[(size_t)(e0 + wv*16 + quad*4 + r)*64 + ct*16 + L] = (_Float16)silu_f(acc[r]);
      }
    }
  } else {
    // ---- embed + layer-0 node linears ----
    float* hs = smem;   // [8][32]
    int rb = blk - PB_SCAT - PB_W3 - PB_RAD;
    int nl = t >> 5, c = t & 31;
    int n = rb * 8 + nl;
    float v = 0.0f;
    #pragma unroll
    for (int j = 0; j < 16; j++) v += x[n*16 + j] * ew[j*32 + c];
    v *= 0.25f;
    hs[nl*32 + c] = v;
    h[(size_t)n*80 + c] = v;
    for (int idx = t; idx < 8*48; idx += 256) {
      int nn = rb * 8 + idx / 48;
      h[(size_t)nn*80 + 32 + idx % 48] = 0.0f;
    }
    __syncthreads();
    for (int idx = t; idx < 2*8*80; idx += 256) {
      int which = idx / 640, r = idx % 640;
      int nl2 = r / 80, cc = r % 80;
      int n2 = rb * 8 + nl2;
      float o = 0.0f;
      if (cc < 32) {
        const float* W = which ? sws0 : lws0;
        #pragma unroll 8
        for (int u = 0; u < 32; u++) o += hs[nl2*32 + u] * W[u*32 + cc];
        o *= 0.17677669529663687f;
      }
      if (which) xself[(size_t)n2*80 + cc] = o;
      else       hx[(size_t)n2*80 + cc] = (_Float16)o;
    }
  }
}

// ---------------- fused MFMA weight-GEMM (f16) + tensor product -> msg (CSR order) ----
// R16-EXACT K-loop — FROZEN (R15/R17: any restructuring spills at the 128-VGPR cap).
// Prologue/epilogue-only deltas: hx gathered as f16 (R21), msg stored f16 (R20).
__launch_bounds__(256, 2)
__global__ void edge_msg_kernel(const int* __restrict__ ei, const float* __restrict__ egeo,
                                const _Float16* __restrict__ f_h,
                                const _Float16* __restrict__ hx,
                                const _Float16* __restrict__ w3h,
                                const float* __restrict__ b3g,
                                const int* __restrict__ epos,
                                _Float16* __restrict__ msg, int l) {
  __shared__ float smem[15616];            // 62.5 KB
  __shared__ int eposS[64];
  float* sT    = smem;                     // [32][64]
  float* p2T   = smem + 2048;              // [16][64]
  float* q3T   = smem + 3072;              // [48][64]  s_u * y1_i
  float* vT    = smem + 6144;              // [48][64]
  float* q5T   = smem + 9216;              // [48][64]
  float* biasL = smem + 12288;             // [3328]
  float* poolA = smem;                     // post-loop overlay (sT+p2T dead)
  float* poolB = smem + 3072;              // overlay (q3T dead)
  float* poolC = smem + 6144;              // overlay (vT dead)

  const int t = threadIdx.x;
  const int e0 = blockIdx.x * 64;
  const float* b3l = b3g + (size_t)l * WNUM;

  // ---- prologue ----
  for (int i = t; i < WNUM; i += 256) biasL[i] = b3l[i];
  if (t < 64) eposS[t] = epos[e0 + t];
  for (int idx = t; idx < 64*80; idx += 256) {
    int e = idx / 80, c = idx % 80;
    int src = ei[e0 + e];
    float val = (float)hx[(size_t)src*80 + c];
    if (c < 32) sT[c*64 + e] = val; else vT[(c-32)*64 + e] = val;
  }
  __syncthreads();
  for (int idx = t; idx < 64*16; idx += 256) {
    int u = idx >> 6, e = idx & 63;
    const float* g = &egeo[(size_t)(e0+e)*20];
    float a = vT[(u*3)*64+e]*g[0] + vT[(u*3+1)*64+e]*g[1] + vT[(u*3+2)*64+e]*g[2];
    p2T[u*64 + e] = a * 0.5773502691896258f;
  }
  for (int idx = t; idx < 64*48; idx += 256) {
    int o = idx >> 6, e = idx & 63;
    int u = o / 3, jj = o % 3;
    const float* g = &egeo[(size_t)(e0+e)*20];
    q3T[o*64 + e] = sT[u*64 + e] * g[jj];
    float a = vT[(u*3)*64+e]*g[3+jj] + vT[(u*3+1)*64+e]*g[6+jj] + vT[(u*3+2)*64+e]*g[9+jj];
    q5T[o*64 + e] = a * 0.7745966692414834f;
  }

  const int wv = t >> 6, lane = t & 63, L = lane & 15, quad = lane >> 4;
  const int qb = quad * 4;

  // A fragments for all 4 edge-groups (32 VGPR)
  half8 Ah[4][2];
  #pragma unroll
  for (int g = 0; g < 4; ++g) {
    const half8* fA = (const half8*)(f_h + (size_t)(e0 + g*16 + L)*64);
    Ah[g][0] = fA[quad];
    Ah[g][1] = fA[4 + quad];
  }
  __syncthreads();   // LDS (factors + bias + epos) ready

  const _Float16* wb = w3h + (size_t)l * 208 * 1024 + lane * 8;
  half8 pb0[4], pb1[4];
  float bs[4];

#define PRIME(START)                                                          \
  { _Pragma("unroll")                                                         \
    for (int _s = 0; _s < 4; ++_s) {                                          \
      const _Float16* _wn = wb + (size_t)((START) + _s) * 1024;               \
      pb0[_s] = *(const half8*)_wn;                                           \
      pb1[_s] = *(const half8*)(_wn + 512);                                   \
      bs[_s] = biasL[((START) + _s)*16 + L];                                  \
    } }

  // declares a0..a3 (one per edge-group); CO compile-time
#define GCORE(IDX, CO, OKCOND)                                                \
  f32x4 a0, a1, a2, a3;                                                       \
  { half8 _B0 = pb0[(CO)&3], _B1 = pb1[(CO)&3];                               \
    float _bb = bs[(CO)&3];                                                   \
    if (OKCOND) {                                                             \
      const _Float16* _wn = wb + (size_t)((IDX) + 4) * 1024;                  \
      pb0[(CO)&3] = *(const half8*)_wn;                                       \
      pb1[(CO)&3] = *(const half8*)(_wn + 512);                               \
      bs[(CO)&3] = biasL[((IDX) + 4)*16 + L];                                 \
    }                                                                         \
    a0 = (f32x4){_bb,_bb,_bb,_bb}; a1 = a0; a2 = a0; a3 = a0;                 \
    a0 = __builtin_amdgcn_mfma_f32_16x16x32_f16(Ah[0][0], _B0, a0, 0,0,0);    \
    a0 = __builtin_amdgcn_mfma_f32_16x16x32_f16(Ah[0][1], _B1, a0, 0,0,0);    \
    a1 = __builtin_amdgcn_mfma_f32_16x16x32_f16(Ah[1][0], _B0, a1, 0,0,0);    \
    a1 = __builtin_amdgcn_mfma_f32_16x16x32_f16(Ah[1][1], _B1, a1, 0,0,0);    \
    a2 = __builtin_amdgcn_mfma_f32_16x16x32_f16(Ah[2][0], _B0, a2, 0,0,0);    \
    a2 = __builtin_amdgcn_mfma_f32_16x16x32_f16(Ah[2][1], _B1, a2, 0,0,0);    \
    a3 = __builtin_amdgcn_mfma_f32_16x16x32_f16(Ah[3][0], _B0, a3, 0,0,0);    \
    a3 = __builtin_amdgcn_mfma_f32_16x16x32_f16(Ah[3][1], _B1, a3, 0,0,0);    \
  }

  const float S48 = 0.14433756729740645f;  // 1/sqrt(48)
  const float S64 = 0.125f;                // 1/sqrt(64)

  if (wv <= 1) {
    f32x4 ms[4][3];
    #pragma unroll
    for (int g = 0; g < 4; ++g)
      #pragma unroll
      for (int j = 0; j < 3; ++j) ms[g][j] = (f32x4){0,0,0,0};
    const int ustart = wv * 16, istart = wv * 48, iend = istart + 48;
    PRIME(istart);
    for (int u4 = 0; u4 < 16; u4 += 4) {
      #pragma unroll
      for (int uu = 0; uu < 4; ++uu) {
        const int u = u4 + uu;
        f32x4 f0 = *(const f32x4*)&sT[(ustart+u)*64 + qb];
        f32x4 f1 = *(const f32x4*)&sT[(ustart+u)*64 + 16 + qb];
        f32x4 f2 = *(const f32x4*)&sT[(ustart+u)*64 + 32 + qb];
        f32x4 f3 = *(const f32x4*)&sT[(ustart+u)*64 + 48 + qb];
        #pragma unroll
        for (int j = 0; j < 3; ++j) {
          const int CO = uu*3 + j;
          const int idx = istart + u4*3 + CO;
          GCORE(idx, CO, idx + 4 < iend);
          ms[0][j] += f0*a0; ms[1][j] += f1*a1; ms[2][j] += f2*a2; ms[3][j] += f3*a3;
        }
      }
    }
    float* pool = (wv == 0) ? poolA : poolB;
    __syncthreads();
    #pragma unroll
    for (int g = 0; g < 4; ++g)
      #pragma unroll
      for (int j = 0; j < 3; ++j)
        #pragma unroll
        for (int r = 0; r < 4; ++r)
          pool[(g*16 + qb + r)*48 + j*16 + L] = ms[g][j][r];
    __syncthreads();
  } else if (wv == 2) {
    f32x4 ms[4][3], mv[4][3];
    #pragma unroll
    for (int g = 0; g < 4; ++g)
      #pragma unroll
      for (int j = 0; j < 3; ++j) { ms[g][j] = (f32x4){0,0,0,0}; mv[g][j] = (f32x4){0,0,0,0}; }
    PRIME(96);
    for (int u4 = 0; u4 < 16; u4 += 4) {
      #pragma unroll
      for (int uu = 0; uu < 4; ++uu) {
        const int u = u4 + uu;
        f32x4 f0 = *(const f32x4*)&p2T[u*64 + qb];
        f32x4 f1 = *(const f32x4*)&p2T[u*64 + 16 + qb];
        f32x4 f2 = *(const f32x4*)&p2T[u*64 + 32 + qb];
        f32x4 f3 = *(const f32x4*)&p2T[u*64 + 48 + qb];
        #pragma unroll
        for (int j = 0; j < 3; ++j) {
          const int CO = uu*3 + j;
          const int idx = 96 + u4*3 + CO;
          GCORE(idx, CO, idx + 4 < 144);
          ms[0][j] += f0*a0; ms[1][j] += f1*a1; ms[2][j] += f2*a2; ms[3][j] += f3*a3;
        }
      }
    }
    PRIME(176);
    for (int u4 = 0; u4 < 16; u4 += 4) {
      #pragma unroll
      for (int uu = 0; uu < 4; ++uu) {
        const int u = u4 + uu;
        const int idx = 176 + u;
        GCORE(idx, uu, idx + 4 < 192);
        #pragma unroll
        for (int i = 0; i < 3; ++i) {
          mv[0][i] += *(const f32x4*)&vT[(u*3+i)*64 + qb]      * a0;
          mv[1][i] += *(const f32x4*)&vT[(u*3+i)*64 + 16 + qb] * a1;
          mv[2][i] += *(const f32x4*)&vT[(u*3+i)*64 + 32 + qb] * a2;
          mv[3][i] += *(const f32x4*)&vT[(u*3+i)*64 + 48 + qb] * a3;
        }
      }
    }
    __syncthreads();
    #pragma unroll
    for (int g = 0; g < 4; ++g)
      #pragma unroll
      for (int i = 0; i < 3; ++i)
        #pragma unroll
        for (int r = 0; r < 4; ++r)
          poolC[(g*16 + qb + r)*48 + i*16 + L] = mv[g][i][r];
    __syncthreads();
    #pragma unroll
    for (int g = 0; g < 4; ++g) {
      #pragma unroll
      for (int r = 0; r < 4; ++r) {
        const int eb = g*16 + qb + r;
        _Float16* mp = msg + (size_t)eposS[eb]*96;
        #pragma unroll
        for (int j = 0; j < 3; ++j)
          mp[j*16 + L] = (_Float16)((ms[g][j][r] + poolA[eb*48 + j*16 + L] + poolB[eb*48 + j*16 + L]) * S48);
      }
    }
  } else {
    f32x4 mv[4][3];
    #pragma unroll
    for (int g = 0; g < 4; ++g)
      #pragma unroll
      for (int i = 0; i < 3; ++i) mv[g][i] = (f32x4){0,0,0,0};
    PRIME(144);
    for (int u4 = 0; u4 < 32; u4 += 4) {
      #pragma unroll
      for (int uu = 0; uu < 4; ++uu) {
        const int u = u4 + uu;
        const int idx = 144 + u;
        GCORE(idx, uu, idx + 4 < 176);
        #pragma unroll
        for (int i = 0; i < 3; ++i) {
          mv[0][i] += *(const f32x4*)&q3T[(u*3+i)*64 + qb]      * a0;
          mv[1][i] += *(const f32x4*)&q3T[(u*3+i)*64 + 16 + qb] * a1;
          mv[2][i] += *(const f32x4*)&q3T[(u*3+i)*64 + 32 + qb] * a2;
          mv[3][i] += *(const f32x4*)&q3T[(u*3+i)*64 + 48 + qb] * a3;
        }
      }
    }
    PRIME(192);
    for (int u4 = 0; u4 < 16; u4 += 4) {
      #pragma unroll
      for (int uu = 0; uu < 4; ++uu) {
        const int u = u4 + uu;
        const int idx = 192 + u;
        GCORE(idx, uu, idx + 4 < 208);
        #pragma unroll
        for (int i = 0; i < 3; ++i) {
          mv[0][i] += *(const f32x4*)&q5T[(u*3+i)*64 + qb]      * a0;
          mv[1][i] += *(const f32x4*)&q5T[(u*3+i)*64 + 16 + qb] * a1;
          mv[2][i] += *(const f32x4*)&q5T[(u*3+i)*64 + 32 + qb] * a2;
          mv[3][i] += *(const f32x4*)&q5T[(u*3+i)*64 + 48 + qb] * a3;
        }
      }
    }
    __syncthreads();
    __syncthreads();
    #pragma unroll
    for (int g = 0; g < 4; ++g) {
      #pragma unroll
      for (int r = 0; r < 4; ++r) {
        const int eb = g*16 + qb + r;
        _Float16* mp = msg + (size_t)eposS[eb]*96;
        #pragma unroll
        for (int i = 0; i < 3; ++i)
          mp[48 + 3*L + i] = (_Float16)((mv[g][i][r] + poolC[eb*48 + i*16 + L]) * S64);
      }
    }
  }
#undef GCORE
#undef PRIME
}

// ---------------- fused: CSR-streaming gather (f16 msg) + node update + next linears ----
__global__ void agg_fused_kernel(const _Float16* __restrict__ msg, const int* __restrict__ offs,
                                 const float* __restrict__ xself_in, float* __restrict__ h,
                                 const float* __restrict__ lwsN, const float* __restrict__ lwvN,
                                 const float* __restrict__ swsN, const float* __restrict__ swvN,
                                 _Float16* __restrict__ hx_out, float* __restrict__ xself_out,
                                 const float* __restrict__ pw, float* __restrict__ out,
                                 int last) {
  __shared__ float sagg[4][96];
  __shared__ float hnew[4][80];
  int t = threadIdx.x;
  int nb = blockIdx.x * 4;
  for (int idx = t; idx < 4*96; idx += 256) {
    int nl = idx / 96, c = idx % 96;
    int n = nb + nl;
    int b = offs[n], e = offs[n+1];
    float acc = 0.0f, acc2 = 0.0f;
    int j = b;
    for (; j + 1 < e; j += 2) {
      acc  += (float)msg[(size_t)j*96 + c];
      acc2 += (float)msg[(size_t)(j+1)*96 + c];
    }
    if (j < e) acc += (float)msg[(size_t)j*96 + c];
    sagg[nl][c] = (acc + acc2) * 0.20412414523193154f;   // 1/sqrt(24)
  }
  __syncthreads();
  for (int idx = t; idx < 4*80; idx += 256) {
    int nl = idx / 80, c = idx % 80;
    int n = nb + nl;
    float a;
    if (c < 32) {
      a = silu_f(sagg[nl][c]);
    } else {
      int oc = c - 32, wch = oc / 3;
      a = sagg[nl][48 + oc] * sigm_f(sagg[nl][32 + wch]);
    }
    float hn = h[(size_t)n*80 + c] + xself_in[(size_t)n*80 + c] + a;
    hnew[nl][c] = hn;
    h[(size_t)n*80 + c] = hn;
  }
  __syncthreads();
  if (!last) {
    for (int idx = t; idx < 2*4*80; idx += 256) {
      int which = idx / 320, r = idx % 320;
      int nl = r / 80, c = r % 80;
      int n = nb + nl;
      const float* Ws = which ? swsN : lwsN;
      const float* Wv = which ? swvN : lwvN;
      float v = 0.0f;
      if (c < 32) {
        #pragma unroll 8
        for (int u = 0; u < 32; u++) v += hnew[nl][u] * Ws[u*32 + c];
        v *= 0.17677669529663687f;
      } else {
        int oc = c - 32, wch = oc / 3, i = oc % 3;
        #pragma unroll
        for (int u = 0; u < 16; u++) v += hnew[nl][32 + u*3 + i] * Wv[u*16 + wch];
        v *= 0.25f;
      }
      if (which) xself_out[(size_t)n*80 + c] = v;
      else       hx_out[(size_t)n*80 + c] = (_Float16)v;
    }
  } else {
    for (int idx = t; idx < 4*32; idx += 256) {
      int nl = idx / 32, c = idx % 32;
      int n = nb + nl;
      float acc = 0.0f;
      #pragma unroll 8
      for (int u = 0; u < 32; u++) acc += hnew[nl][u] * pw[u*32 + c];
      out[(size_t)n*32 + c] = acc * 0.17677669529663687f;
    }
  }
}

extern "C" void kernel_launch(void* const* d_in, const int* in_sizes, int n_in,
                              void* d_out, int out_size, void* d_ws, size_t ws_size,
                              hipStream_t stream) {
  const float* x       = (const float*)d_in[0];
  const float* pos     = (const float*)d_in[1];
  const int*   ei      = (const int*)  d_in[2];
  const float* embed_w = (const float*)d_in[3];
  const float* proj_w  = (const float*)d_in[4];
  const float* lin_ws  = (const float*)d_in[5];
  const float* lin_wv  = (const float*)d_in[6];
  const float* sc_ws   = (const float*)d_in[7];
  const float* sc_wv   = (const float*)d_in[8];
  const float* mlp_w1  = (const float*)d_in[9];
  const float* mlp_b1  = (const float*)d_in[10];
  const float* mlp_w2  = (const float*)d_in[11];
  const float* mlp_b2  = (const float*)d_in[12];
  const float* mlp_w3  = (const float*)d_in[13];
  const float* mlp_b3  = (const float*)d_in[14];
  float* out = (float*)d_out;

  float* ws    = (float*)d_ws;
  float* egeo  = ws;                          // NE*20
  float* h     = egeo  + (size_t)NE*20;       // NN*80
  float* xself = h     + (size_t)NN*80;       // NN*80
  _Float16* hx  = (_Float16*)(xself + (size_t)NN*80); // NN*80 f16
  _Float16* msg = hx + (size_t)NN*80;                 // NE*96 f16 (CSR-ordered rows)
  _Float16* f_h = msg + (size_t)NE*96;                // 4*NE*64 f16 (all layers)
  _Float16* w3h = f_h + (size_t)4*NE*64;              // 4*208*1024 f16
  _Float16* w2h = w3h + (size_t)4*208*1024;           // 16384 f16 (32 KB)
  int* cnt    = (int*)(w2h + 16384);          // NN
  int* offs   = cnt + NN;                     // NN+1
  int* cursor = offs + NN + 1;                // NN
  int* epos   = cursor + NN;                  // NE

  hipMemsetAsync(cnt, 0, NN*sizeof(int), stream);
  geom_kernel<<<(NE + 255)/256, 256, 0, stream>>>(pos, ei, egeo, cnt);
  scan_kernel<<<1, 256, 0, stream>>>(cnt, offs, cursor);
  conv_w2_kernel<<<64, 256, 0, stream>>>(mlp_w2, w2h);
  prologue_fused_kernel<<<PB_SCAT + PB_W3 + PB_RAD + PB_EMB, 256, 0, stream>>>(
      ei, cursor, epos, mlp_w3, w3h, w2h, egeo,
      mlp_w1, mlp_b1, mlp_b2, f_h, x, embed_w, lin_ws, sc_ws, h, hx, xself);

  for (int l = 0; l < 4; l++) {
    edge_msg_kernel<<<NE/64, 256, 0, stream>>>(ei, egeo, f_h + (size_t)l*NE*64, hx,
                                               w3h, mlp_b3, epos, msg, l);
    int last = (l == 3);
    agg_fused_kernel<<<NN/4, 256, 0, stream>>>(
        msg, offs, xself, h,
        lin_ws + (size_t)(l+1 < 4 ? l+1 : 0) * 1024,
        lin_wv + (size_t)(l+1 < 4 ? l+1 : 0) * 256,
        sc_ws  + (size_t)(l+1 < 4 ? l+1 : 0) * 1024,
        sc_wv  + (size_t)(l+1 < 4 ? l+1 : 0) * 256,
        hx, xself, proj_w, out, last);
  }
}

// Round 23
// 427.795 us; speedup vs baseline: 1.5529x; 1.0049x over previous
//
#include <hip/hip_runtime.h>
#include <math.h>

#define NN 2048
#define NE 49152
#define WNUM 3328

typedef __attribute__((ext_vector_type(8))) _Float16 half8;
typedef __attribute__((ext_vector_type(4))) float f32x4;

__device__ __forceinline__ float silu_f(float x){ return x / (1.0f + expf(-x)); }
__device__ __forceinline__ float sigm_f(float x){ return 1.0f / (1.0f + expf(-x)); }

// ---------------- fused: edge geometry (192 blocks) | conv_w2 (64 blocks) ----------------
// Independent outputs (egeo/cnt vs w2h), both consumed only by LATER launches — safe
// (R21 lesson: no intra-launch producer-consumer pairs).
#define GB_GEO 192
__global__ void geom_w2_kernel(const float* __restrict__ pos, const int* __restrict__ ei,
                               float* __restrict__ egeo, int* __restrict__ cnt,
                               const float* __restrict__ w2g, _Float16* __restrict__ w2h) {
  if (blockIdx.x >= GB_GEO) {
    // ---- conv_w2: W2 -> f16, MFMA-B-fragment-ordered ----
    int tid = (blockIdx.x - GB_GEO) * 256 + threadIdx.x;
    int j = tid & 7, lane = (tid >> 3) & 63, plane = (tid >> 9) & 1;
    int ct = (tid >> 10) & 3, l = tid >> 12;
    int q = lane >> 4, Lc = lane & 15;
    int k = plane*32 + q*8 + j;
    int n = ct*16 + Lc;
    w2h[tid] = (_Float16)w2g[(size_t)l*4096 + k*64 + n];
    return;
  }
  int e = blockIdx.x * 256 + threadIdx.x;
  int s = ei[e], d = ei[NE + e];
  atomicAdd(&cnt[d], 1);
  float rx = pos[d*3+0] - pos[s*3+0];
  float ry = pos[d*3+1] - pos[s*3+1];
  float rz = pos[d*3+2] - pos[s*3+2];
  float r = sqrtf(rx*rx + ry*ry + rz*rz);
  r = fmaxf(r, 1e-6f);
  float x = rx / r, y = ry / r, z = rz / r;
  const float s3 = 1.7320508075688772f;
  const float c15 = 3.872983346207417f;
  float y2_0 = c15 * x * y;
  float y2_1 = c15 * y * z;
  float y2_2 = 1.118033988749895f * (3.0f*z*z - 1.0f);
  float y2_3 = c15 * x * z;
  float y2_4 = 1.9364916731037085f * (x*x - y*y);
  const float q2 = 0.7071067811865476f;
  const float q6 = 0.4082482904638631f;
  float* g = egeo + (size_t)e * 20;
  g[0] = s3 * x; g[1] = s3 * y; g[2] = s3 * z;
  g[3+0] = -q6*y2_2 + q2*y2_4;
  g[3+1] =  q2*y2_0;
  g[3+2] =  q2*y2_3;
  g[3+3] =  q2*y2_0;
  g[3+4] = -q6*y2_2 - q2*y2_4;
  g[3+5] =  q2*y2_1;
  g[3+6] =  q2*y2_3;
  g[3+7] =  q2*y2_1;
  g[3+8] =  2.0f*q6*y2_2;
  float u = r / 6.0f;
  float fc = 0.0f;
  if (u < 1.0f) {
    float u2=u*u, u3=u2*u, u6=u3*u3, u7=u6*u, u8=u7*u;
    fc = 1.0f - 28.0f*u6 + 48.0f*u7 - 21.0f*u8;
  }
  const float pref = 0.5773502691896258f;
  const float pi6 = 0.5235987755982988f;
  #pragma unroll
  for (int n = 1; n <= 8; n++) {
    g[12 + n - 1] = pref * sinf((float)n * pi6 * r) / r * fc;
  }
}

// ---------------- CSR scan ----------------
__global__ void scan_kernel(const int* __restrict__ cnt, int* __restrict__ offs,
                            int* __restrict__ cursor) {
  __shared__ int part[256];
  int t = threadIdx.x;
  int local[8];
  int s = 0;
  #pragma unroll
  for (int j = 0; j < 8; j++) { local[j] = s; s += cnt[t*8 + j]; }
  part[t] = s;
  __syncthreads();
  for (int off = 1; off < 256; off <<= 1) {
    int v = part[t];
    int add = (t >= off) ? part[t - off] : 0;
    __syncthreads();
    part[t] = v + add;
    __syncthreads();
  }
  int excl = (t == 0) ? 0 : part[t-1];
  #pragma unroll
  for (int j = 0; j < 8; j++) {
    int o = excl + local[j];
    offs[t*8 + j] = o;
    cursor[t*8 + j] = o;
  }
  if (t == 255) offs[2048] = part[255];
}

// ---------------- fused prologue: scatter | conv_w3 | radial_mfma | embed ----
// All sub-kernels depend only on earlier launches; mutually independent.
#define PB_SCAT  192                 // scatter: NE/256
#define PB_W3    208                 // conv_w3: (16*WNUM+255)/256
#define PB_RAD   3072                // radial: 4*(NE/64)
#define PB_EMB   256                 // embed_prep: NN/8
__global__ void prologue_fused_kernel(
    const int* __restrict__ ei, int* __restrict__ cursor, int* __restrict__ epos,
    const float* __restrict__ w3g, _Float16* __restrict__ w3h,
    const _Float16* __restrict__ w2h,
    const float* __restrict__ egeo,
    const float* __restrict__ w1, const float* __restrict__ b1,
    const float* __restrict__ b2, _Float16* __restrict__ f_h,
    const float* __restrict__ x, const float* __restrict__ ew,
    const float* __restrict__ lws0, const float* __restrict__ sws0,
    float* __restrict__ h, _Float16* __restrict__ hx, float* __restrict__ xself) {
  __shared__ float smem[2304];   // radial h1s (64*72 f16) / embed hs
  const int blk = blockIdx.x;
  const int t = threadIdx.x;

  if (blk < PB_SCAT) {
    int e = blk * 256 + t;
    int d = ei[NE + e];
    int p = atomicAdd(&cursor[d], 1);
    epos[e] = p;
  } else if (blk < PB_SCAT + PB_W3) {
    int tid = (blk - PB_SCAT) * 256 + t;
    if (tid >= 16 * WNUM) return;
    int n = tid % WNUM;
    int lq = tid / WNUM;
    int quad = lq & 3, l = lq >> 2;
    const float* src = w3g + (size_t)l * 64 * WNUM + n;
    int idx = n >> 4, L = n & 15;
    _Float16* dst = w3h + ((size_t)(l * 208 + idx) * 2) * 512 + (quad*16 + L) * 8;
    half8 h0, h1;
    #pragma unroll
    for (int j = 0; j < 8; j++) {
      h0[j] = (_Float16)src[(size_t)(quad*8 + j) * WNUM];
      h1[j] = (_Float16)src[(size_t)(32 + quad*8 + j) * WNUM];
    }
    *(half8*)(dst)       = h0;
    *(half8*)(dst + 512) = h1;
  } else if (blk < PB_SCAT + PB_W3 + PB_RAD) {
    // ---- radial MFMA (reads w2h from the geom_w2 launch — safe) ----
    _Float16* h1s = (_Float16*)smem;   // 64*72 f16
    int rb = blk - PB_SCAT - PB_W3;
    const int l = rb / (NE/64);
    const int e0 = (rb % (NE/64)) * 64;
    const float* w1l = w1 + (size_t)l * 512;
    _Float16* fl = f_h + (size_t)l * NE * 64;
    {
      int e = t >> 2, jb = (t & 3) * 16;
      const float* rbp = egeo + (size_t)(e0 + e) * 20 + 12;
      float r0 = rbp[0], r1 = rbp[1], r2 = rbp[2], r3 = rbp[3];
      float r4 = rbp[4], r5 = rbp[5], r6 = rbp[6], r7 = rbp[7];
      #pragma unroll
      for (int jj = 0; jj < 16; ++jj) {
        int j = jb + jj;
        float acc = b1[l*64 + j];
        acc += r0 * w1l[0*64 + j];
        acc += r1 * w1l[1*64 + j];
        acc += r2 * w1l[2*64 + j];
        acc += r3 * w1l[3*64 + j];
        acc += r4 * w1l[4*64 + j];
        acc += r5 * w1l[5*64 + j];
        acc += r6 * w1l[6*64 + j];
        acc += r7 * w1l[7*64 + j];
        h1s[e*72 + j] = (_Float16)silu_f(acc);
      }
    }
    __syncthreads();
    const int wv = t >> 6, lane = t & 63, L = lane & 15, quad = lane >> 4;
    half8 A0 = *(const half8*)&h1s[(wv*16 + L)*72 + quad*8];
    half8 A1 = *(const half8*)&h1s[(wv*16 + L)*72 + 32 + quad*8];
    #pragma unroll
    for (int ct = 0; ct < 4; ++ct) {
      const _Float16* wB = w2h + ((size_t)(l*4 + ct) * 2) * 512 + lane*8;
      half8 B0 = *(const half8*)(wB);
      half8 B1 = *(const half8*)(wB + 512);
      float bb = b2[l*64 + ct*16 + L];
      f32x4 acc = {bb, bb, bb, bb};
      acc = __builtin_amdgcn_mfma_f32_16x16x32_f16(A0, B0, acc, 0, 0, 0);
      acc = __builtin_amdgcn_mfma_f32_16x16x32_f16(A1, B1, acc, 0, 0, 0);
      #pragma unroll
      for (int r = 0; r < 4; ++r) {
        fl[(size_t)(e0 + wv*16 + quad*4 + r)*64 + ct*16 + L] = (_Float16)silu_f(acc[r]);
      }
    }
  } else {
    // ---- embed + layer-0 node linears ----
    float* hs = smem;   // [8][32]
    int rb = blk - PB_SCAT - PB_W3 - PB_RAD;
    int nl = t >> 5, c = t & 31;
    int n = rb * 8 + nl;
    float v = 0.0f;
    #pragma unroll
    for (int j = 0; j < 16; j++) v += x[n*16 + j] * ew[j*32 + c];
    v *= 0.25f;
    hs[nl*32 + c] = v;
    h[(size_t)n*80 + c] = v;
    for (int idx = t; idx < 8*48; idx += 256) {
      int nn = rb * 8 + idx / 48;
      h[(size_t)nn*80 + 32 + idx % 48] = 0.0f;
    }
    __syncthreads();
    for (int idx = t; idx < 2*8*80; idx += 256) {
      int which = idx / 640, r = idx % 640;
      int nl2 = r / 80, cc = r % 80;
      int n2 = rb * 8 + nl2;
      float o = 0.0f;
      if (cc < 32) {
        const float* W = which ? sws0 : lws0;
        #pragma unroll 8
        for (int u = 0; u < 32; u++) o += hs[nl2*32 + u] * W[u*32 + cc];
        o *= 0.17677669529663687f;
      }
      if (which) xself[(size_t)n2*80 + cc] = o;
      else       hx[(size_t)n2*80 + cc] = (_Float16)o;
    }
  }
}

// ---------------- fused MFMA weight-GEMM (f16) + tensor product -> msg (CSR order) ----
// R16-EXACT K-loop — FROZEN (R15/R17: any restructuring spills at the 128-VGPR cap).
// Prologue/epilogue-only deltas: hx gathered as f16 (R22), msg stored f16 (R20).
__launch_bounds__(256, 2)
__global__ void edge_msg_kernel(const int* __restrict__ ei, const float* __restrict__ egeo,
                                const _Float16* __restrict__ f_h,
                                const _Float16* __restrict__ hx,
                                const _Float16* __restrict__ w3h,
                                const float* __restrict__ b3g,
                                const int* __restrict__ epos,
                                _Float16* __restrict__ msg, int l) {
  __shared__ float smem[15616];            // 62.5 KB
  __shared__ int eposS[64];
  float* sT    = smem;                     // [32][64]
  float* p2T   = smem + 2048;              // [16][64]
  float* q3T   = smem + 3072;              // [48][64]  s_u * y1_i
  float* vT    = smem + 6144;              // [48][64]
  float* q5T   = smem + 9216;              // [48][64]
  float* biasL = smem + 12288;             // [3328]
  float* poolA = smem;                     // post-loop overlay (sT+p2T dead)
  float* poolB = smem + 3072;              // overlay (q3T dead)
  float* poolC = smem + 6144;              // overlay (vT dead)

  const int t = threadIdx.x;
  const int e0 = blockIdx.x * 64;
  const float* b3l = b3g + (size_t)l * WNUM;

  // ---- prologue ----
  for (int i = t; i < WNUM; i += 256) biasL[i] = b3l[i];
  if (t < 64) eposS[t] = epos[e0 + t];
  for (int idx = t; idx < 64*80; idx += 256) {
    int e = idx / 80, c = idx % 80;
    int src = ei[e0 + e];
    float val = (float)hx[(size_t)src*80 + c];
    if (c < 32) sT[c*64 + e] = val; else vT[(c-32)*64 + e] = val;
  }
  __syncthreads();
  for (int idx = t; idx < 64*16; idx += 256) {
    int u = idx >> 6, e = idx & 63;
    const float* g = &egeo[(size_t)(e0+e)*20];
    float a = vT[(u*3)*64+e]*g[0] + vT[(u*3+1)*64+e]*g[1] + vT[(u*3+2)*64+e]*g[2];
    p2T[u*64 + e] = a * 0.5773502691896258f;
  }
  for (int idx = t; idx < 64*48; idx += 256) {
    int o = idx >> 6, e = idx & 63;
    int u = o / 3, jj = o % 3;
    const float* g = &egeo[(size_t)(e0+e)*20];
    q3T[o*64 + e] = sT[u*64 + e] * g[jj];
    float a = vT[(u*3)*64+e]*g[3+jj] + vT[(u*3+1)*64+e]*g[6+jj] + vT[(u*3+2)*64+e]*g[9+jj];
    q5T[o*64 + e] = a * 0.7745966692414834f;
  }

  const int wv = t >> 6, lane = t & 63, L = lane & 15, quad = lane >> 4;
  const int qb = quad * 4;

  // A fragments for all 4 edge-groups (32 VGPR)
  half8 Ah[4][2];
  #pragma unroll
  for (int g = 0; g < 4; ++g) {
    const half8* fA = (const half8*)(f_h + (size_t)(e0 + g*16 + L)*64);
    Ah[g][0] = fA[quad];
    Ah[g][1] = fA[4 + quad];
  }
  __syncthreads();   // LDS (factors + bias + epos) ready

  const _Float16* wb = w3h + (size_t)l * 208 * 1024 + lane * 8;
  half8 pb0[4], pb1[4];
  float bs[4];

#define PRIME(START)                                                          \
  { _Pragma("unroll")                                                         \
    for (int _s = 0; _s < 4; ++_s) {                                          \
      const _Float16* _wn = wb + (size_t)((START) + _s) * 1024;               \
      pb0[_s] = *(const half8*)_wn;                                           \
      pb1[_s] = *(const half8*)(_wn + 512);                                   \
      bs[_s] = biasL[((START) + _s)*16 + L];                                  \
    } }

  // declares a0..a3 (one per edge-group); CO compile-time
#define GCORE(IDX, CO, OKCOND)                                                \
  f32x4 a0, a1, a2, a3;                                                       \
  { half8 _B0 = pb0[(CO)&3], _B1 = pb1[(CO)&3];                               \
    float _bb = bs[(CO)&3];                                                   \
    if (OKCOND) {                                                             \
      const _Float16* _wn = wb + (size_t)((IDX) + 4) * 1024;                  \
      pb0[(CO)&3] = *(const half8*)_wn;                                       \
      pb1[(CO)&3] = *(const half8*)(_wn + 512);                               \
      bs[(CO)&3] = biasL[((IDX) + 4)*16 + L];                                 \
    }                                                                         \
    a0 = (f32x4){_bb,_bb,_bb,_bb}; a1 = a0; a2 = a0; a3 = a0;                 \
    a0 = __builtin_amdgcn_mfma_f32_16x16x32_f16(Ah[0][0], _B0, a0, 0,0,0);    \
    a0 = __builtin_amdgcn_mfma_f32_16x16x32_f16(Ah[0][1], _B1, a0, 0,0,0);    \
    a1 = __builtin_amdgcn_mfma_f32_16x16x32_f16(Ah[1][0], _B0, a1, 0,0,0);    \
    a1 = __builtin_amdgcn_mfma_f32_16x16x32_f16(Ah[1][1], _B1, a1, 0,0,0);    \
    a2 = __builtin_amdgcn_mfma_f32_16x16x32_f16(Ah[2][0], _B0, a2, 0,0,0);    \
    a2 = __builtin_amdgcn_mfma_f32_16x16x32_f16(Ah[2][1], _B1, a2, 0,0,0);    \
    a3 = __builtin_amdgcn_mfma_f32_16x16x32_f16(Ah[3][0], _B0, a3, 0,0,0);    \
    a3 = __builtin_amdgcn_mfma_f32_16x16x32_f16(Ah[3][1], _B1, a3, 0,0,0);    \
  }

  const float S48 = 0.14433756729740645f;  // 1/sqrt(48)
  const float S64 = 0.125f;                // 1/sqrt(64)

  if (wv <= 1) {
    f32x4 ms[4][3];
    #pragma unroll
    for (int g = 0; g < 4; ++g)
      #pragma unroll
      for (int j = 0; j < 3; ++j) ms[g][j] = (f32x4){0,0,0,0};
    const int ustart = wv * 16, istart = wv * 48, iend = istart + 48;
    PRIME(istart);
    for (int u4 = 0; u4 < 16; u4 += 4) {
      #pragma unroll
      for (int uu = 0; uu < 4; ++uu) {
        const int u = u4 + uu;
        f32x4 f0 = *(const f32x4*)&sT[(ustart+u)*64 + qb];
        f32x4 f1 = *(const f32x4*)&sT[(ustart+u)*64 + 16 + qb];
        f32x4 f2 = *(const f32x4*)&sT[(ustart+u)*64 + 32 + qb];
        f32x4 f3 = *(const f32x4*)&sT[(ustart+u)*64 + 48 + qb];
        #pragma unroll
        for (int j = 0; j < 3; ++j) {
          const int CO = uu*3 + j;
          const int idx = istart + u4*3 + CO;
          GCORE(idx, CO, idx + 4 < iend);
          ms[0][j] += f0*a0; ms[1][j] += f1*a1; ms[2][j] += f2*a2; ms[3][j] += f3*a3;
        }
      }
    }
    float* pool = (wv == 0) ? poolA : poolB;
    __syncthreads();
    #pragma unroll
    for (int g = 0; g < 4; ++g)
      #pragma unroll
      for (int j = 0; j < 3; ++j)
        #pragma unroll
        for (int r = 0; r < 4; ++r)
          pool[(g*16 + qb + r)*48 + j*16 + L] = ms[g][j][r];
    __syncthreads();
  } else if (wv == 2) {
    f32x4 ms[4][3], mv[4][3];
    #pragma unroll
    for (int g = 0; g < 4; ++g)
      #pragma unroll
      for (int j = 0; j < 3; ++j) { ms[g][j] = (f32x4){0,0,0,0}; mv[g][j] = (f32x4){0,0,0,0}; }
    PRIME(96);
    for (int u4 = 0; u4 < 16; u4 += 4) {
      #pragma unroll
      for (int uu = 0; uu < 4; ++uu) {
        const int u = u4 + uu;
        f32x4 f0 = *(const f32x4*)&p2T[u*64 + qb];
        f32x4 f1 = *(const f32x4*)&p2T[u*64 + 16 + qb];
        f32x4 f2 = *(const f32x4*)&p2T[u*64 + 32 + qb];
        f32x4 f3 = *(const f32x4*)&p2T[u*64 + 48 + qb];
        #pragma unroll
        for (int j = 0; j < 3; ++j) {
          const int CO = uu*3 + j;
          const int idx = 96 + u4*3 + CO;
          GCORE(idx, CO, idx + 4 < 144);
          ms[0][j] += f0*a0; ms[1][j] += f1*a1; ms[2][j] += f2*a2; ms[3][j] += f3*a3;
        }
      }
    }
    PRIME(176);
    for (int u4 = 0; u4 < 16; u4 += 4) {
      #pragma unroll
      for (int uu = 0; uu < 4; ++uu) {
        const int u = u4 + uu;
        const int idx = 176 + u;
        GCORE(idx, uu, idx + 4 < 192);
        #pragma unroll
        for (int i = 0; i < 3; ++i) {
          mv[0][i] += *(const f32x4*)&vT[(u*3+i)*64 + qb]      * a0;
          mv[1][i] += *(const f32x4*)&vT[(u*3+i)*64 + 16 + qb] * a1;
          mv[2][i] += *(const f32x4*)&vT[(u*3+i)*64 + 32 + qb] * a2;
          mv[3][i] += *(const f32x4*)&vT[(u*3+i)*64 + 48 + qb] * a3;
        }
      }
    }
    __syncthreads();
    #pragma unroll
    for (int g = 0; g < 4; ++g)
      #pragma unroll
      for (int i = 0; i < 3; ++i)
        #pragma unroll
        for (int r = 0; r < 4; ++r)
          poolC[(g*16 + qb + r)*48 + i*16 + L] = mv[g][i][r];
    __syncthreads();
    #pragma unroll
    for (int g = 0; g < 4; ++g) {
      #pragma unroll
      for (int r = 0; r < 4; ++r) {
        const int eb = g*16 + qb + r;
        _Float16* mp = msg + (size_t)eposS[eb]*96;
        #pragma unroll
        for (int j = 0; j < 3; ++j)
          mp[j*16 + L] = (_Float16)((ms[g][j][r] + poolA[eb*48 + j*16 + L] + poolB[eb*48 + j*16 + L]) * S48);
      }
    }
  } else {
    f32x4 mv[4][3];
    #pragma unroll
    for (int g = 0; g < 4; ++g)
      #pragma unroll
      for (int i = 0; i < 3; ++i) mv[g][i] = (f32x4){0,0,0,0};
    PRIME(144);
    for (int u4 = 0; u4 < 32; u4 += 4) {
      #pragma unroll
      for (int uu = 0; uu < 4; ++uu) {
        const int u = u4 + uu;
        const int idx = 144 + u;
        GCORE(idx, uu, idx + 4 < 176);
        #pragma unroll
        for (int i = 0; i < 3; ++i) {
          mv[0][i] += *(const f32x4*)&q3T[(u*3+i)*64 + qb]      * a0;
          mv[1][i] += *(const f32x4*)&q3T[(u*3+i)*64 + 16 + qb] * a1;
          mv[2][i] += *(const f32x4*)&q3T[(u*3+i)*64 + 32 + qb] * a2;
          mv[3][i] += *(const f32x4*)&q3T[(u*3+i)*64 + 48 + qb] * a3;
        }
      }
    }
    PRIME(192);
    for (int u4 = 0; u4 < 16; u4 += 4) {
      #pragma unroll
      for (int uu = 0; uu < 4; ++uu) {
        const int u = u4 + uu;
        const int idx = 192 + u;
        GCORE(idx, uu, idx + 4 < 208);
        #pragma unroll
        for (int i = 0; i < 3; ++i) {
          mv[0][i] += *(const f32x4*)&q5T[(u*3+i)*64 + qb]      * a0;
          mv[1][i] += *(const f32x4*)&q5T[(u*3+i)*64 + 16 + qb] * a1;
          mv[2][i] += *(const f32x4*)&q5T[(u*3+i)*64 + 32 + qb] * a2;
          mv[3][i] += *(const f32x4*)&q5T[(u*3+i)*64 + 48 + qb] * a3;
        }
      }
    }
    __syncthreads();
    __syncthreads();
    #pragma unroll
    for (int g = 0; g < 4; ++g) {
      #pragma unroll
      for (int r = 0; r < 4; ++r) {
        const int eb = g*16 + qb + r;
        _Float16* mp = msg + (size_t)eposS[eb]*96;
        #pragma unroll
        for (int i = 0; i < 3; ++i)
          mp[48 + 3*L + i] = (_Float16)((mv[g][i][r] + poolC[eb*48 + i*16 + L]) * S64);
      }
    }
  }
#undef GCORE
#undef PRIME
}

// ---------------- fused: CSR-streaming gather (f16 msg) + node update + next linears ----
__global__ void agg_fused_kernel(const _Float16* __restrict__ msg, const int* __restrict__ offs,
                                 const float* __restrict__ xself_in, float* __restrict__ h,
                                 const float* __restrict__ lwsN, const float* __restrict__ lwvN,
                                 const float* __restrict__ swsN, const float* __restrict__ swvN,
                                 _Float16* __restrict__ hx_out, float* __restrict__ xself_out,
                                 const float* __restrict__ pw, float* __restrict__ out,
                                 int last) {
  __shared__ float sagg[4][96];
  __shared__ float hnew[4][80];
  int t = threadIdx.x;
  int nb = blockIdx.x * 4;
  for (int idx = t; idx < 4*96; idx += 256) {
    int nl = idx / 96, c = idx % 96;
    int n = nb + nl;
    int b = offs[n], e = offs[n+1];
    float acc = 0.0f, acc2 = 0.0f;
    int j = b;
    for (; j + 1 < e; j += 2) {
      acc  += (float)msg[(size_t)j*96 + c];
      acc2 += (float)msg[(size_t)(j+1)*96 + c];
    }
    if (j < e) acc += (float)msg[(size_t)j*96 + c];
    sagg[nl][c] = (acc + acc2) * 0.20412414523193154f;   // 1/sqrt(24)
  }
  __syncthreads();
  for (int idx = t; idx < 4*80; idx += 256) {
    int nl = idx / 80, c = idx % 80;
    int n = nb + nl;
    float a;
    if (c < 32) {
      a = silu_f(sagg[nl][c]);
    } else {
      int oc = c - 32, wch = oc / 3;
      a = sagg[nl][48 + oc] * sigm_f(sagg[nl][32 + wch]);
    }
    float hn = h[(size_t)n*80 + c] + xself_in[(size_t)n*80 + c] + a;
    hnew[nl][c] = hn;
    h[(size_t)n*80 + c] = hn;
  }
  __syncthreads();
  if (!last) {
    for (int idx = t; idx < 2*4*80; idx += 256) {
      int which = idx / 320, r = idx % 320;
      int nl = r / 80, c = r % 80;
      int n = nb + nl;
      const float* Ws = which ? swsN : lwsN;
      const float* Wv = which ? swvN : lwvN;
      float v = 0.0f;
      if (c < 32) {
        #pragma unroll 8
        for (int u = 0; u < 32; u++) v += hnew[nl][u] * Ws[u*32 + c];
        v *= 0.17677669529663687f;
      } else {
        int oc = c - 32, wch = oc / 3, i = oc % 3;
        #pragma unroll
        for (int u = 0; u < 16; u++) v += hnew[nl][32 + u*3 + i] * Wv[u*16 + wch];
        v *= 0.25f;
      }
      if (which) xself_out[(size_t)n*80 + c] = v;
      else       hx_out[(size_t)n*80 + c] = (_Float16)v;
    }
  } else {
    for (int idx = t; idx < 4*32; idx += 256) {
      int nl = idx / 32, c = idx % 32;
      int n = nb + nl;
      float acc = 0.0f;
      #pragma unroll 8
      for (int u = 0; u < 32; u++) acc += hnew[nl][u] * pw[u*32 + c];
      out[(size_t)n*32 + c] = acc * 0.17677669529663687f;
    }
  }
}

extern "C" void kernel_launch(void* const* d_in, const int* in_sizes, int n_in,
                              void* d_out, int out_size, void* d_ws, size_t ws_size,
                              hipStream_t stream) {
  const float* x       = (const float*)d_in[0];
  const float* pos     = (const float*)d_in[1];
  const int*   ei      = (const int*)  d_in[2];
  const float* embed_w = (const float*)d_in[3];
  const float* proj_w  = (const float*)d_in[4];
  const float* lin_ws  = (const float*)d_in[5];
  const float* lin_wv  = (const float*)d_in[6];
  const float* sc_ws   = (const float*)d_in[7];
  const float* sc_wv   = (const float*)d_in[8];
  const float* mlp_w1  = (const float*)d_in[9];
  const float* mlp_b1  = (const float*)d_in[10];
  const float* mlp_w2  = (const float*)d_in[11];
  const float* mlp_b2  = (const float*)d_in[12];
  const float* mlp_w3  = (const float*)d_in[13];
  const float* mlp_b3  = (const float*)d_in[14];
  float* out = (float*)d_out;

  float* ws    = (float*)d_ws;
  float* egeo  = ws;                          // NE*20
  float* h     = egeo  + (size_t)NE*20;       // NN*80
  float* xself = h     + (size_t)NN*80;       // NN*80
  _Float16* hx  = (_Float16*)(xself + (size_t)NN*80); // NN*80 f16
  _Float16* msg = hx + (size_t)NN*80;                 // NE*96 f16 (CSR-ordered rows)
  _Float16* f_h = msg + (size_t)NE*96;                // 4*NE*64 f16 (all layers)
  _Float16* w3h = f_h + (size_t)4*NE*64;              // 4*208*1024 f16
  _Float16* w2h = w3h + (size_t)4*208*1024;           // 16384 f16 (32 KB)
  int* cnt    = (int*)(w2h + 16384);          // NN
  int* offs   = cnt + NN;                     // NN+1
  int* cursor = offs + NN + 1;                // NN
  int* epos   = cursor + NN;                  // NE

  hipMemsetAsync(cnt, 0, NN*sizeof(int), stream);
  geom_w2_kernel<<<GB_GEO + 64, 256, 0, stream>>>(pos, ei, egeo, cnt, mlp_w2, w2h);
  scan_kernel<<<1, 256, 0, stream>>>(cnt, offs, cursor);
  prologue_fused_kernel<<<PB_SCAT + PB_W3 + PB_RAD + PB_EMB, 256, 0, stream>>>(
      ei, cursor, epos, mlp_w3, w3h, w2h, egeo,
      mlp_w1, mlp_b1, mlp_b2, f_h, x, embed_w, lin_ws, sc_ws, h, hx, xself);

  for (int l = 0; l < 4; l++) {
    edge_msg_kernel<<<NE/64, 256, 0, stream>>>(ei, egeo, f_h + (size_t)l*NE*64, hx,
                                               w3h, mlp_b3, epos, msg, l);
    int last = (l == 3);
    agg_fused_kernel<<<NN/4, 256, 0, stream>>>(
        msg, offs, xself, h,
        lin_ws + (size_t)(l+1 < 4 ? l+1 : 0) * 1024,
        lin_wv + (size_t)(l+1 < 4 ? l+1 : 0) * 256,
        sc_ws  + (size_t)(l+1 < 4 ? l+1 : 0) * 1024,
        sc_wv  + (size_t)(l+1 < 4 ? l+1 : 0) * 256,
        hx, xself, proj_w, out, last);
  }
}